// Round 3
// baseline (549.914 us; speedup 1.0000x reference)
//
#include <hip/hip_runtime.h>
#include <hip/hip_bf16.h>

#define B_   2
#define S_   2048
#define HID_ 2048
#define H_   16
#define KVH_ 4
#define D_   128
#define M_   4096
#define NQKV 3072

typedef __attribute__((ext_vector_type(8))) short bf16x8;   // 8 bf16 = 4 VGPR
typedef __attribute__((ext_vector_type(4))) float f32x4;
typedef const __attribute__((address_space(1))) unsigned int* gas_p;
typedef __attribute__((address_space(3))) unsigned int* las_p;

__device__ __forceinline__ unsigned short f2b(float f) {
    __hip_bfloat16 h = __float2bfloat16(f);
    return *reinterpret_cast<unsigned short*>(&h);
}
__device__ __forceinline__ float b2f(unsigned short u) {
    __hip_bfloat16 h;
    *reinterpret_cast<unsigned short*>(&h) = u;
    return __bfloat162float(h);
}

// ---- DPP 16-lane reductions (xor15, xor7, xor2, xor1 closure) -------------
#define DPPF(x, ctrl) __int_as_float(__builtin_amdgcn_update_dpp(0, __float_as_int(x), ctrl, 0xF, 0xF, true))
__device__ __forceinline__ float row16_max(float x) {
    x = fmaxf(x, DPPF(x, 0x140));   // row_mirror      (lane ^ 15)
    x = fmaxf(x, DPPF(x, 0x141));   // row_half_mirror (lane ^ 7)
    x = fmaxf(x, DPPF(x, 0x4E));    // quad_perm [2,3,0,1] (lane ^ 2)
    x = fmaxf(x, DPPF(x, 0xB1));    // quad_perm [1,0,3,2] (lane ^ 1)
    return x;
}
__device__ __forceinline__ float row16_sum(float x) {
    x += DPPF(x, 0x140);
    x += DPPF(x, 0x141);
    x += DPPF(x, 0x4E);
    x += DPPF(x, 0xB1);
    return x;
}

// ---------- convert x: fp32 -> bf16 ----------------------------------------
__global__ __launch_bounds__(256)
void convert_x(const float* __restrict__ x, unsigned short* __restrict__ xb) {
    int i = (blockIdx.x * 256 + threadIdx.x) * 4;
    float4 v = *(const float4*)(x + i);
    ushort4 o;
    o.x = f2b(v.x); o.y = f2b(v.y); o.z = f2b(v.z); o.w = f2b(v.w);
    *(ushort4*)(xb + i) = o;
}

// ---------- convert + transpose weight: w[2048][N] fp32 -> wt[n][k] bf16 ---
__global__ __launch_bounds__(256)
void convert_w_t(const float* __restrict__ w, int N,
                 unsigned short* __restrict__ wt, int nbase) {
    __shared__ float tile[32][33];
    int tx = threadIdx.x & 31, ty = threadIdx.x >> 5;
    int n0 = blockIdx.x * 32, k0 = blockIdx.y * 32;
    #pragma unroll
    for (int j = 0; j < 4; j++)
        tile[ty + j*8][tx] = w[(size_t)(k0 + ty + j*8) * N + n0 + tx];
    __syncthreads();
    #pragma unroll
    for (int j = 0; j < 4; j++)
        wt[(size_t)(nbase + n0 + ty + j*8) * 2048 + k0 + tx] = f2b(tile[tx][ty + j*8]);
}

// ---------- MFMA GEMM (m97 structure): C = A[M][2048] * BT[N][2048]^T ------
// 128x128 tile, BK=32, unpadded LDS, global_load_lds width-16 staging.
// LDS dest must be wave-uniform base + lane*16: chunk c -> LDS byte c*16,
// global row c>>2, 16B-quarter c&3 (row = 64B = 4 chunks, linear).
template<bool BF16OUT>
__global__ __launch_bounds__(256)
void gemm_bt(const unsigned short* __restrict__ A,
             const unsigned short* __restrict__ BT,
             void* __restrict__ Cv, int N) {
    __shared__ unsigned short As[128][32];
    __shared__ unsigned short Bs[128][32];

    int tid  = threadIdx.x;
    int lane = tid & 63, w = tid >> 6;
    int quad = lane >> 4, l15 = lane & 15;
    int row0 = blockIdx.y * 128, col0 = blockIdx.x * 128;
    int wm = (w & 1) * 64, wn = (w >> 1) * 64;

    f32x4 acc[4][4];
    const f32x4 zf = {0.f, 0.f, 0.f, 0.f};
    #pragma unroll
    for (int i = 0; i < 4; i++)
        #pragma unroll
        for (int j = 0; j < 4; j++) acc[i][j] = zf;

    const unsigned short* Arow = A  + (size_t)row0 * 2048;
    const unsigned short* Brow = BT + (size_t)col0 * 2048;

    for (int k0 = 0; k0 < 2048; k0 += 32) {
        #pragma unroll
        for (int it = 0; it < 2; it++) {
            int c = w * 128 + it * 64 + lane;          // chunk id 0..511
            int r = c >> 2, q8 = (c & 3) * 8;
            __builtin_amdgcn_global_load_lds(
                (gas_p)(Arow + (size_t)r * 2048 + k0 + q8),
                (las_p)((char*)&As[0][0] + (size_t)(w * 128 + it * 64) * 16),
                16, 0, 0);
            __builtin_amdgcn_global_load_lds(
                (gas_p)(Brow + (size_t)r * 2048 + k0 + q8),
                (las_p)((char*)&Bs[0][0] + (size_t)(w * 128 + it * 64) * 16),
                16, 0, 0);
        }
        __syncthreads();
        bf16x8 af[4], bf[4];
        #pragma unroll
        for (int i = 0; i < 4; i++) af[i] = *(const bf16x8*)&As[wm + i*16 + l15][quad * 8];
        #pragma unroll
        for (int j = 0; j < 4; j++) bf[j] = *(const bf16x8*)&Bs[wn + j*16 + l15][quad * 8];
        #pragma unroll
        for (int i = 0; i < 4; i++)
            #pragma unroll
            for (int j = 0; j < 4; j++)
                acc[i][j] = __builtin_amdgcn_mfma_f32_16x16x32_bf16(af[i], bf[j], acc[i][j], 0, 0, 0);
        __syncthreads();
    }

    // C/D layout: col = lane&15, row = quad*4 + reg
    #pragma unroll
    for (int i = 0; i < 4; i++)
        #pragma unroll
        for (int j = 0; j < 4; j++)
            #pragma unroll
            for (int r = 0; r < 4; r++) {
                size_t idx = (size_t)(row0 + wm + i*16 + quad*4 + r) * N + col0 + wn + j*16 + l15;
                if (BF16OUT) ((unsigned short*)Cv)[idx] = f2b(acc[i][j][r]);
                else         ((float*)Cv)[idx] = acc[i][j][r];
            }
}

// ---------- RoPE on Q,K region (cols 0..2559), in place --------------------
__global__ __launch_bounds__(256)
void rope_kernel(unsigned short* __restrict__ qkv, const float* __restrict__ freqs) {
    int p = blockIdx.x * 256 + threadIdx.x;
    int m = p / 1280;
    int cp = p - m * 1280;
    int col = cp * 2;
    int s = m & (S_ - 1);
    int d = col & (D_ - 1);
    unsigned short* ptr = qkv + (size_t)m * NQKV + col;
    ushort2 uv = *(ushort2*)ptr;
    float xr = b2f(uv.x), xi = b2f(uv.y);
    float cs = freqs[s * 128 + d], sn = freqs[s * 128 + d + 1];
    ushort2 ov;
    ov.x = f2b(xr * cs - xi * sn);
    ov.y = f2b(xr * sn + xi * cs);
    *(ushort2*)ptr = ov;
}

// ---------- transpose V region -> vT[(b*512 + kvcol)][s] -------------------
__global__ __launch_bounds__(256)
void v_transpose(const unsigned short* __restrict__ qkv, unsigned short* __restrict__ vT) {
    __shared__ unsigned short tile[32][34];
    int tx = threadIdx.x & 31, ty = threadIdx.x >> 5;
    int s0 = blockIdx.x * 32;
    int c0 = blockIdx.y * 32;
    int b  = blockIdx.z;
    #pragma unroll
    for (int j = 0; j < 4; j++)
        tile[ty + j*8][tx] = qkv[(size_t)(b*2048 + s0 + ty + j*8) * NQKV + 2560 + c0 + tx];
    __syncthreads();
    #pragma unroll
    for (int j = 0; j < 4; j++)
        vT[(size_t)(b*512 + c0 + ty + j*8) * 2048 + s0 + tx] = tile[tx][ty + j*8];
}

// ---------- MFMA flash attention -------------------------------------------
// Q-frags in registers (no Q LDS -> 44KB LDS -> 3 blocks/CU); next K/V tile
// prefetched into registers during compute; DPP softmax reductions.
__global__ __launch_bounds__(256, 3)
void attn_mfma(const unsigned short* __restrict__ qkv,
               const unsigned short* __restrict__ vT,
               unsigned short* __restrict__ ao) {
    __shared__ unsigned short Ks[64][136];   // 272B stride: 2-way = free
    __shared__ unsigned short Vt[128][72];   // 144B stride: 2-way = free
    __shared__ unsigned short Ps[4][16][72]; // per-wave P round-trip

    int tid  = threadIdx.x;
    int lane = tid & 63, w = tid >> 6;
    int quad = lane >> 4, l15 = lane & 15;
    int qt = blockIdx.x, h = blockIdx.y, b = blockIdx.z;
    int hk = h >> 2;
    int q0 = qt * 64;
    const float scale = 0.08838834764831845f;

    // Q fragments straight to registers: A-row = l15, k = k4*32 + quad*8
    bf16x8 aq[4];
    {
        const unsigned short* qrow = qkv + (size_t)(b*2048 + q0 + w*16 + l15) * NQKV + h*128;
        #pragma unroll
        for (int k4 = 0; k4 < 4; k4++)
            aq[k4] = *(const bf16x8*)(qrow + k4*32 + quad*8);
    }

    const unsigned short* kb0 = qkv + (size_t)(b*2048) * NQKV + 2048 + hk*128;
    const unsigned short* vb0 = vT + (size_t)(b*512 + hk*128) * 2048;

    uint4 kreg[4], vreg[4];
    auto issue = [&](int kt) {
        #pragma unroll
        for (int it = 0; it < 4; it++) {
            int c = tid + it * 256;
            kreg[it] = *(const uint4*)(kb0 + (size_t)(kt*64 + (c >> 4)) * NQKV + (c & 15) * 8);
            vreg[it] = *(const uint4*)(vb0 + (size_t)(c >> 3) * 2048 + kt*64 + (c & 7) * 8);
        }
    };
    auto commit = [&]() {
        #pragma unroll
        for (int it = 0; it < 4; it++) {
            int c = tid + it * 256;
            *(uint4*)&Ks[c >> 4][(c & 15) * 8] = kreg[it];
            *(uint4*)&Vt[c >> 3][(c & 7) * 8]  = vreg[it];
        }
    };

    f32x4 o_acc[8];
    const f32x4 zf = {0.f, 0.f, 0.f, 0.f};
    #pragma unroll
    for (int jn = 0; jn < 8; jn++) o_acc[jn] = zf;
    float m_i[4], l_i[4];
    #pragma unroll
    for (int r = 0; r < 4; r++) { m_i[r] = -1e30f; l_i[r] = 0.f; }

    issue(0);
    for (int kt = 0; kt <= qt; kt++) {
        __syncthreads();                   // prior tile fully consumed
        commit();
        __syncthreads();
        if (kt < qt) issue(kt + 1);        // hide global latency behind compute

        // ---- S = Q K^T ----
        f32x4 s_acc[4];
        #pragma unroll
        for (int j = 0; j < 4; j++) {
            s_acc[j] = zf;
            #pragma unroll
            for (int k4 = 0; k4 < 4; k4++) {
                bf16x8 bk = *(const bf16x8*)&Ks[j*16 + l15][k4*32 + quad*8];
                s_acc[j] = __builtin_amdgcn_mfma_f32_16x16x32_bf16(aq[k4], bk, s_acc[j], 0, 0, 0);
            }
        }

        // ---- mask + scale ----
        float sv[4][4];
        if (kt == qt) {
            #pragma unroll
            for (int j = 0; j < 4; j++)
                #pragma unroll
                for (int r = 0; r < 4; r++) {
                    float v = s_acc[j][r] * scale;
                    sv[j][r] = (j*16 + l15 <= w*16 + quad*4 + r) ? v : -1e30f;
                }
        } else {
            #pragma unroll
            for (int j = 0; j < 4; j++)
                #pragma unroll
                for (int r = 0; r < 4; r++) sv[j][r] = s_acc[j][r] * scale;
        }

        // ---- online softmax, DPP reductions ----
        #pragma unroll
        for (int r = 0; r < 4; r++) {
            float rmax = fmaxf(fmaxf(sv[0][r], sv[1][r]), fmaxf(sv[2][r], sv[3][r]));
            rmax = row16_max(rmax);
            float mnew = fmaxf(m_i[r], rmax);
            float alpha = __expf(m_i[r] - mnew);
            float rs = 0.f;
            #pragma unroll
            for (int j = 0; j < 4; j++) {
                float p = __expf(sv[j][r] - mnew);
                Ps[w][quad*4 + r][j*16 + l15] = f2b(p);
                rs += p;
            }
            rs = row16_sum(rs);
            l_i[r] = l_i[r] * alpha + rs;
            m_i[r] = mnew;
            #pragma unroll
            for (int jn = 0; jn < 8; jn++) o_acc[jn][r] *= alpha;
        }

        // ---- PV (same-wave LDS round trip; no barrier needed) ----
        bf16x8 ap0 = *(const bf16x8*)&Ps[w][l15][quad*8];
        bf16x8 ap1 = *(const bf16x8*)&Ps[w][l15][32 + quad*8];
        #pragma unroll
        for (int jn = 0; jn < 8; jn++) {
            bf16x8 bv0 = *(const bf16x8*)&Vt[jn*16 + l15][quad*8];
            bf16x8 bv1 = *(const bf16x8*)&Vt[jn*16 + l15][32 + quad*8];
            o_acc[jn] = __builtin_amdgcn_mfma_f32_16x16x32_bf16(ap0, bv0, o_acc[jn], 0, 0, 0);
            o_acc[jn] = __builtin_amdgcn_mfma_f32_16x16x32_bf16(ap1, bv1, o_acc[jn], 0, 0, 0);
        }
    }

    #pragma unroll
    for (int r = 0; r < 4; r++) {
        float inv = 1.f / l_i[r];
        size_t base = (size_t)(b*2048 + q0 + w*16 + quad*4 + r) * 2048 + h*128;
        #pragma unroll
        for (int jn = 0; jn < 8; jn++)
            ao[base + jn*16 + l15] = f2b(o_acc[jn][r] * inv);
    }
}

// ---------- launch ---------------------------------------------------------
extern "C" void kernel_launch(void* const* d_in, const int* in_sizes, int n_in,
                              void* d_out, int out_size, void* d_ws, size_t ws_size,
                              hipStream_t stream) {
    const float* x     = (const float*)d_in[0];
    const float* freqs = (const float*)d_in[1];
    const float* wq    = (const float*)d_in[2];
    const float* wk    = (const float*)d_in[3];
    const float* wv    = (const float*)d_in[4];
    const float* wo    = (const float*)d_in[5];
    float* out = (float*)d_out;

    char* ws = (char*)d_ws;
    unsigned short* xbf    = (unsigned short*)(ws);                  // 16MB
    unsigned short* aobuf  = (unsigned short*)(ws);                  // alias (xbf dead)
    unsigned short* wqkvT  = (unsigned short*)(ws + (16u<<20));      // 12MB
    unsigned short* woT    = (unsigned short*)(ws + (28u<<20));      // 8MB
    unsigned short* qkvbuf = (unsigned short*)(ws + (36u<<20));      // 24MB
    unsigned short* vTbuf  = (unsigned short*)(ws + (60u<<20));      // 4MB

    dim3 blk(256);
    convert_x<<<8192, blk, 0, stream>>>(x, xbf);
    convert_w_t<<<dim3(64, 64), blk, 0, stream>>>(wq, 2048, wqkvT, 0);
    convert_w_t<<<dim3(16, 64), blk, 0, stream>>>(wk,  512, wqkvT, 2048);
    convert_w_t<<<dim3(16, 64), blk, 0, stream>>>(wv,  512, wqkvT, 2560);
    convert_w_t<<<dim3(64, 64), blk, 0, stream>>>(wo, 2048, woT, 0);

    gemm_bt<true><<<dim3(NQKV/128, M_/128), blk, 0, stream>>>(xbf, wqkvT, qkvbuf, NQKV);
    rope_kernel<<<20480, blk, 0, stream>>>(qkvbuf, freqs);
    v_transpose<<<dim3(64, 16, 2), blk, 0, stream>>>(qkvbuf, vTbuf);
    attn_mfma<<<dim3(32, 16, 2), blk, 0, stream>>>(qkvbuf, vTbuf, aobuf);
    gemm_bt<false><<<dim3(2048/128, M_/128), blk, 0, stream>>>(aobuf, woT, out, 2048);
}

// Round 4
// 381.378 us; speedup vs baseline: 1.4419x; 1.4419x over previous
//
#include <hip/hip_runtime.h>
#include <hip/hip_bf16.h>

#define B_   2
#define S_   2048
#define HID_ 2048
#define H_   16
#define KVH_ 4
#define D_   128
#define M_   4096
#define NQKV 3072

typedef __attribute__((ext_vector_type(8))) short bf16x8;   // 8 bf16 = 4 VGPR
typedef __attribute__((ext_vector_type(4))) float f32x4;
typedef const __attribute__((address_space(1))) unsigned int* gas_p;
typedef __attribute__((address_space(3))) unsigned int* las_p;

__device__ __forceinline__ unsigned short f2b(float f) {
    __hip_bfloat16 h = __float2bfloat16(f);
    return *reinterpret_cast<unsigned short*>(&h);
}
__device__ __forceinline__ float b2f(unsigned short u) {
    __hip_bfloat16 h;
    *reinterpret_cast<unsigned short*>(&h) = u;
    return __bfloat162float(h);
}

// ---- DPP 16-lane reductions (xor15, xor7, xor2, xor1 closure) -------------
#define DPPF(x, ctrl) __int_as_float(__builtin_amdgcn_update_dpp(0, __float_as_int(x), ctrl, 0xF, 0xF, true))
__device__ __forceinline__ float row16_max(float x) {
    x = fmaxf(x, DPPF(x, 0x140));   // row_mirror      (lane ^ 15)
    x = fmaxf(x, DPPF(x, 0x141));   // row_half_mirror (lane ^ 7)
    x = fmaxf(x, DPPF(x, 0x4E));    // quad_perm [2,3,0,1] (lane ^ 2)
    x = fmaxf(x, DPPF(x, 0xB1));    // quad_perm [1,0,3,2] (lane ^ 1)
    return x;
}
__device__ __forceinline__ float row16_sum(float x) {
    x += DPPF(x, 0x140);
    x += DPPF(x, 0x141);
    x += DPPF(x, 0x4E);
    x += DPPF(x, 0xB1);
    return x;
}

// ---------- convert x: fp32 -> bf16 ----------------------------------------
__global__ __launch_bounds__(256)
void convert_x(const float* __restrict__ x, unsigned short* __restrict__ xb) {
    int i = (blockIdx.x * 256 + threadIdx.x) * 4;
    float4 v = *(const float4*)(x + i);
    ushort4 o;
    o.x = f2b(v.x); o.y = f2b(v.y); o.z = f2b(v.z); o.w = f2b(v.w);
    *(ushort4*)(xb + i) = o;
}

// ---------- convert + transpose weight: w[2048][N] fp32 -> wt[n][k] bf16 ---
__global__ __launch_bounds__(256)
void convert_w_t(const float* __restrict__ w, int N,
                 unsigned short* __restrict__ wt, int nbase) {
    __shared__ float tile[32][33];
    int tx = threadIdx.x & 31, ty = threadIdx.x >> 5;
    int n0 = blockIdx.x * 32, k0 = blockIdx.y * 32;
    #pragma unroll
    for (int j = 0; j < 4; j++)
        tile[ty + j*8][tx] = w[(size_t)(k0 + ty + j*8) * N + n0 + tx];
    __syncthreads();
    #pragma unroll
    for (int j = 0; j < 4; j++)
        wt[(size_t)(nbase + n0 + ty + j*8) * 2048 + k0 + tx] = f2b(tile[tx][ty + j*8]);
}

// ---------- MFMA GEMM (m97 structure): C = A[M][2048] * BT[N][2048]^T ------
template<bool BF16OUT>
__global__ __launch_bounds__(256)
void gemm_bt(const unsigned short* __restrict__ A,
             const unsigned short* __restrict__ BT,
             void* __restrict__ Cv, int N) {
    __shared__ unsigned short As[128][32];
    __shared__ unsigned short Bs[128][32];

    int tid  = threadIdx.x;
    int lane = tid & 63, w = tid >> 6;
    int quad = lane >> 4, l15 = lane & 15;
    int row0 = blockIdx.y * 128, col0 = blockIdx.x * 128;
    int wm = (w & 1) * 64, wn = (w >> 1) * 64;

    f32x4 acc[4][4];
    const f32x4 zf = {0.f, 0.f, 0.f, 0.f};
    #pragma unroll
    for (int i = 0; i < 4; i++)
        #pragma unroll
        for (int j = 0; j < 4; j++) acc[i][j] = zf;

    const unsigned short* Arow = A  + (size_t)row0 * 2048;
    const unsigned short* Brow = BT + (size_t)col0 * 2048;

    for (int k0 = 0; k0 < 2048; k0 += 32) {
        #pragma unroll
        for (int it = 0; it < 2; it++) {
            int c = w * 128 + it * 64 + lane;
            int r = c >> 2, q8 = (c & 3) * 8;
            __builtin_amdgcn_global_load_lds(
                (gas_p)(Arow + (size_t)r * 2048 + k0 + q8),
                (las_p)((char*)&As[0][0] + (size_t)(w * 128 + it * 64) * 16),
                16, 0, 0);
            __builtin_amdgcn_global_load_lds(
                (gas_p)(Brow + (size_t)r * 2048 + k0 + q8),
                (las_p)((char*)&Bs[0][0] + (size_t)(w * 128 + it * 64) * 16),
                16, 0, 0);
        }
        __syncthreads();
        bf16x8 af[4], bf[4];
        #pragma unroll
        for (int i = 0; i < 4; i++) af[i] = *(const bf16x8*)&As[wm + i*16 + l15][quad * 8];
        #pragma unroll
        for (int j = 0; j < 4; j++) bf[j] = *(const bf16x8*)&Bs[wn + j*16 + l15][quad * 8];
        #pragma unroll
        for (int i = 0; i < 4; i++)
            #pragma unroll
            for (int j = 0; j < 4; j++)
                acc[i][j] = __builtin_amdgcn_mfma_f32_16x16x32_bf16(af[i], bf[j], acc[i][j], 0, 0, 0);
        __syncthreads();
    }

    #pragma unroll
    for (int i = 0; i < 4; i++)
        #pragma unroll
        for (int j = 0; j < 4; j++)
            #pragma unroll
            for (int r = 0; r < 4; r++) {
                size_t idx = (size_t)(row0 + wm + i*16 + quad*4 + r) * N + col0 + wn + j*16 + l15;
                if (BF16OUT) ((unsigned short*)Cv)[idx] = f2b(acc[i][j][r]);
                else         ((float*)Cv)[idx] = acc[i][j][r];
            }
}

// ---------- RoPE on Q,K region (cols 0..2559), in place --------------------
__global__ __launch_bounds__(256)
void rope_kernel(unsigned short* __restrict__ qkv, const float* __restrict__ freqs) {
    int p = blockIdx.x * 256 + threadIdx.x;
    int m = p / 1280;
    int cp = p - m * 1280;
    int col = cp * 2;
    int s = m & (S_ - 1);
    int d = col & (D_ - 1);
    unsigned short* ptr = qkv + (size_t)m * NQKV + col;
    ushort2 uv = *(ushort2*)ptr;
    float xr = b2f(uv.x), xi = b2f(uv.y);
    float cs = freqs[s * 128 + d], sn = freqs[s * 128 + d + 1];
    ushort2 ov;
    ov.x = f2b(xr * cs - xi * sn);
    ov.y = f2b(xr * sn + xi * cs);
    *(ushort2*)ptr = ov;
}

// ---------- transpose V region -> vT[(b*512 + kvcol)][s] -------------------
__global__ __launch_bounds__(256)
void v_transpose(const unsigned short* __restrict__ qkv, unsigned short* __restrict__ vT) {
    __shared__ unsigned short tile[32][34];
    int tx = threadIdx.x & 31, ty = threadIdx.x >> 5;
    int s0 = blockIdx.x * 32;
    int c0 = blockIdx.y * 32;
    int b  = blockIdx.z;
    #pragma unroll
    for (int j = 0; j < 4; j++)
        tile[ty + j*8][tx] = qkv[(size_t)(b*2048 + s0 + ty + j*8) * NQKV + 2560 + c0 + tx];
    __syncthreads();
    #pragma unroll
    for (int j = 0; j < 4; j++)
        vT[(size_t)(b*512 + c0 + ty + j*8) * 2048 + s0 + tx] = tile[tx][ty + j*8];
}

// ---------- MFMA flash attention -------------------------------------------
// Double-buffered K/V staging via global_load_lds (async, zero VGPR cost);
// XOR-swizzled LDS layout (no padding possible with lds-dma): K chunk q at
// slot q^(row&15), V chunk q at slot q^(row&7) -> frag b128 reads spread 16
// lanes over all 8 bank groups (2-way = free). One barrier per k-tile; the
// vmcnt drain at the barrier lands AFTER a full tile of compute, so staging
// latency is hidden. Q-frags in registers; DPP softmax reductions.
__global__ __launch_bounds__(256)
void attn_mfma(const unsigned short* __restrict__ qkv,
               const unsigned short* __restrict__ vT,
               unsigned short* __restrict__ ao) {
    __shared__ unsigned short Ks[2][64 * 128];   // 16KB per buffer, swizzled
    __shared__ unsigned short Vt[2][128 * 64];   // 16KB per buffer, swizzled
    __shared__ unsigned short Ps[4][16][72];     // per-wave P round-trip

    int tid  = threadIdx.x;
    int lane = tid & 63, w = tid >> 6;
    int quad = lane >> 4, l15 = lane & 15;
    int qt = blockIdx.x, h = blockIdx.y, b = blockIdx.z;
    int hk = h >> 2;
    int q0 = qt * 64;
    const float scale = 0.08838834764831845f;

    // Q fragments straight to registers: A-row = l15, k = k4*32 + quad*8
    bf16x8 aq[4];
    {
        const unsigned short* qrow = qkv + (size_t)(b*2048 + q0 + w*16 + l15) * NQKV + h*128;
        #pragma unroll
        for (int k4 = 0; k4 < 4; k4++)
            aq[k4] = *(const bf16x8*)(qrow + k4*32 + quad*8);
    }

    const unsigned short* kb0 = qkv + (size_t)(b*2048) * NQKV + 2048 + hk*128;
    const unsigned short* vb0 = vT + (size_t)(b*512 + hk*128) * 2048;

    // async staging of tile kt into buffer `buf` (1024 16B-chunks each of K,V)
    auto stage = [&](int kt, int buf) {
        #pragma unroll
        for (int it = 0; it < 4; it++) {
            int s = w * 256 + it * 64 + lane;       // LDS slot (16B units)
            int r = s >> 4, qp = s & 15;
            int q = qp ^ (r & 15);                  // inverse swizzle on source
            __builtin_amdgcn_global_load_lds(
                (gas_p)(kb0 + (size_t)(kt*64 + r) * NQKV + q * 8),
                (las_p)((char*)&Ks[buf][0] + (w * 256 + it * 64) * 16),
                16, 0, 0);
        }
        #pragma unroll
        for (int it = 0; it < 4; it++) {
            int s = w * 256 + it * 64 + lane;
            int r = s >> 3, qp = s & 7;
            int q = qp ^ (r & 7);
            __builtin_amdgcn_global_load_lds(
                (gas_p)(vb0 + (size_t)r * 2048 + kt*64 + q * 8),
                (las_p)((char*)&Vt[buf][0] + (w * 256 + it * 64) * 16),
                16, 0, 0);
        }
    };

    f32x4 o_acc[8];
    const f32x4 zf = {0.f, 0.f, 0.f, 0.f};
    #pragma unroll
    for (int jn = 0; jn < 8; jn++) o_acc[jn] = zf;
    float m_i[4], l_i[4];
    #pragma unroll
    for (int r = 0; r < 4; r++) { m_i[r] = -1e30f; l_i[r] = 0.f; }

    stage(0, 0);
    for (int kt = 0; kt <= qt; kt++) {
        int cur = kt & 1;
        __syncthreads();                 // tile kt landed; prev buffer free
        if (kt < qt) stage(kt + 1, cur ^ 1);   // in flight during compute

        // ---- S = Q K^T ----
        f32x4 s_acc[4];
        #pragma unroll
        for (int j = 0; j < 4; j++) {
            s_acc[j] = zf;
            int krow = j*16 + l15;
            #pragma unroll
            for (int k4 = 0; k4 < 4; k4++) {
                int chunk = (k4*4 + quad) ^ l15;       // krow & 15 == l15
                bf16x8 bk = *(const bf16x8*)&Ks[cur][(krow*16 + chunk) * 8];
                s_acc[j] = __builtin_amdgcn_mfma_f32_16x16x32_bf16(aq[k4], bk, s_acc[j], 0, 0, 0);
            }
        }

        // ---- mask + scale ----
        float sv[4][4];
        if (kt == qt) {
            #pragma unroll
            for (int j = 0; j < 4; j++)
                #pragma unroll
                for (int r = 0; r < 4; r++) {
                    float v = s_acc[j][r] * scale;
                    sv[j][r] = (j*16 + l15 <= w*16 + quad*4 + r) ? v : -1e30f;
                }
        } else {
            #pragma unroll
            for (int j = 0; j < 4; j++)
                #pragma unroll
                for (int r = 0; r < 4; r++) sv[j][r] = s_acc[j][r] * scale;
        }

        // ---- online softmax, DPP reductions ----
        #pragma unroll
        for (int r = 0; r < 4; r++) {
            float rmax = fmaxf(fmaxf(sv[0][r], sv[1][r]), fmaxf(sv[2][r], sv[3][r]));
            rmax = row16_max(rmax);
            float mnew = fmaxf(m_i[r], rmax);
            float alpha = __expf(m_i[r] - mnew);
            float rs = 0.f;
            #pragma unroll
            for (int j = 0; j < 4; j++) {
                float p = __expf(sv[j][r] - mnew);
                Ps[w][quad*4 + r][j*16 + l15] = f2b(p);
                rs += p;
            }
            rs = row16_sum(rs);
            l_i[r] = l_i[r] * alpha + rs;
            m_i[r] = mnew;
            #pragma unroll
            for (int jn = 0; jn < 8; jn++) o_acc[jn][r] *= alpha;
        }

        // ---- PV (same-wave LDS round trip) ----
        bf16x8 ap0 = *(const bf16x8*)&Ps[w][l15][quad*8];
        bf16x8 ap1 = *(const bf16x8*)&Ps[w][l15][32 + quad*8];
        #pragma unroll
        for (int jn = 0; jn < 8; jn++) {
            int vrow = jn*16 + l15;
            int c0 = quad ^ (vrow & 7);
            int c1 = (4 + quad) ^ (vrow & 7);
            bf16x8 bv0 = *(const bf16x8*)&Vt[cur][(vrow*8 + c0) * 8];
            bf16x8 bv1 = *(const bf16x8*)&Vt[cur][(vrow*8 + c1) * 8];
            o_acc[jn] = __builtin_amdgcn_mfma_f32_16x16x32_bf16(ap0, bv0, o_acc[jn], 0, 0, 0);
            o_acc[jn] = __builtin_amdgcn_mfma_f32_16x16x32_bf16(ap1, bv1, o_acc[jn], 0, 0, 0);
        }
    }

    #pragma unroll
    for (int r = 0; r < 4; r++) {
        float inv = 1.f / l_i[r];
        size_t base = (size_t)(b*2048 + q0 + w*16 + quad*4 + r) * 2048 + h*128;
        #pragma unroll
        for (int jn = 0; jn < 8; jn++)
            ao[base + jn*16 + l15] = f2b(o_acc[jn][r] * inv);
    }
}

// ---------- launch ---------------------------------------------------------
extern "C" void kernel_launch(void* const* d_in, const int* in_sizes, int n_in,
                              void* d_out, int out_size, void* d_ws, size_t ws_size,
                              hipStream_t stream) {
    const float* x     = (const float*)d_in[0];
    const float* freqs = (const float*)d_in[1];
    const float* wq    = (const float*)d_in[2];
    const float* wk    = (const float*)d_in[3];
    const float* wv    = (const float*)d_in[4];
    const float* wo    = (const float*)d_in[5];
    float* out = (float*)d_out;

    char* ws = (char*)d_ws;
    unsigned short* xbf    = (unsigned short*)(ws);                  // 16MB
    unsigned short* aobuf  = (unsigned short*)(ws);                  // alias (xbf dead)
    unsigned short* wqkvT  = (unsigned short*)(ws + (16u<<20));      // 12MB
    unsigned short* woT    = (unsigned short*)(ws + (28u<<20));      // 8MB
    unsigned short* qkvbuf = (unsigned short*)(ws + (36u<<20));      // 24MB
    unsigned short* vTbuf  = (unsigned short*)(ws + (60u<<20));      // 4MB

    dim3 blk(256);
    convert_x<<<8192, blk, 0, stream>>>(x, xbf);
    convert_w_t<<<dim3(64, 64), blk, 0, stream>>>(wq, 2048, wqkvT, 0);
    convert_w_t<<<dim3(16, 64), blk, 0, stream>>>(wk,  512, wqkvT, 2048);
    convert_w_t<<<dim3(16, 64), blk, 0, stream>>>(wv,  512, wqkvT, 2560);
    convert_w_t<<<dim3(64, 64), blk, 0, stream>>>(wo, 2048, woT, 0);

    gemm_bt<true><<<dim3(NQKV/128, M_/128), blk, 0, stream>>>(xbf, wqkvT, qkvbuf, NQKV);
    rope_kernel<<<20480, blk, 0, stream>>>(qkvbuf, freqs);
    v_transpose<<<dim3(64, 16, 2), blk, 0, stream>>>(qkvbuf, vTbuf);
    attn_mfma<<<dim3(32, 16, 2), blk, 0, stream>>>(qkvbuf, vTbuf, aobuf);
    gemm_bt<false><<<dim3(2048/128, M_/128), blk, 0, stream>>>(aobuf, woT, out, 2048);
}

// Round 5
// 371.768 us; speedup vs baseline: 1.4792x; 1.0258x over previous
//
#include <hip/hip_runtime.h>
#include <hip/hip_bf16.h>

#define B_   2
#define S_   2048
#define HID_ 2048
#define H_   16
#define KVH_ 4
#define D_   128
#define M_   4096
#define NQKV 3072

typedef __attribute__((ext_vector_type(8))) short bf16x8;   // 8 bf16 = 4 VGPR
typedef __attribute__((ext_vector_type(4))) float f32x4;
typedef const __attribute__((address_space(1))) unsigned int* gas_p;
typedef __attribute__((address_space(3))) unsigned int* las_p;

__device__ __forceinline__ unsigned short f2b(float f) {
    __hip_bfloat16 h = __float2bfloat16(f);
    return *reinterpret_cast<unsigned short*>(&h);
}
__device__ __forceinline__ float b2f(unsigned short u) {
    __hip_bfloat16 h;
    *reinterpret_cast<unsigned short*>(&h) = u;
    return __bfloat162float(h);
}

// ---------- convert x: fp32 -> bf16 ----------------------------------------
__global__ __launch_bounds__(256)
void convert_x(const float* __restrict__ x, unsigned short* __restrict__ xb) {
    int i = (blockIdx.x * 256 + threadIdx.x) * 4;
    float4 v = *(const float4*)(x + i);
    ushort4 o;
    o.x = f2b(v.x); o.y = f2b(v.y); o.z = f2b(v.z); o.w = f2b(v.w);
    *(ushort4*)(xb + i) = o;
}

// ---------- convert + transpose weight: w[2048][N] fp32 -> wt[n][k] bf16 ---
__global__ __launch_bounds__(256)
void convert_w_t(const float* __restrict__ w, int N,
                 unsigned short* __restrict__ wt, int nbase) {
    __shared__ float tile[32][33];
    int tx = threadIdx.x & 31, ty = threadIdx.x >> 5;
    int n0 = blockIdx.x * 32, k0 = blockIdx.y * 32;
    #pragma unroll
    for (int j = 0; j < 4; j++)
        tile[ty + j*8][tx] = w[(size_t)(k0 + ty + j*8) * N + n0 + tx];
    __syncthreads();
    #pragma unroll
    for (int j = 0; j < 4; j++)
        wt[(size_t)(nbase + n0 + ty + j*8) * 2048 + k0 + tx] = f2b(tile[tx][ty + j*8]);
}

// ---------- MFMA GEMM (m97 structure): C = A[M][2048] * BT[N][2048]^T ------
template<bool BF16OUT>
__global__ __launch_bounds__(256)
void gemm_bt(const unsigned short* __restrict__ A,
             const unsigned short* __restrict__ BT,
             void* __restrict__ Cv, int N) {
    __shared__ unsigned short As[128][32];
    __shared__ unsigned short Bs[128][32];

    int tid  = threadIdx.x;
    int lane = tid & 63, w = tid >> 6;
    int quad = lane >> 4, l15 = lane & 15;
    int row0 = blockIdx.y * 128, col0 = blockIdx.x * 128;
    int wm = (w & 1) * 64, wn = (w >> 1) * 64;

    f32x4 acc[4][4];
    const f32x4 zf = {0.f, 0.f, 0.f, 0.f};
    #pragma unroll
    for (int i = 0; i < 4; i++)
        #pragma unroll
        for (int j = 0; j < 4; j++) acc[i][j] = zf;

    const unsigned short* Arow = A  + (size_t)row0 * 2048;
    const unsigned short* Brow = BT + (size_t)col0 * 2048;

    for (int k0 = 0; k0 < 2048; k0 += 32) {
        #pragma unroll
        for (int it = 0; it < 2; it++) {
            int c = w * 128 + it * 64 + lane;
            int r = c >> 2, q8 = (c & 3) * 8;
            __builtin_amdgcn_global_load_lds(
                (gas_p)(Arow + (size_t)r * 2048 + k0 + q8),
                (las_p)((char*)&As[0][0] + (size_t)(w * 128 + it * 64) * 16),
                16, 0, 0);
            __builtin_amdgcn_global_load_lds(
                (gas_p)(Brow + (size_t)r * 2048 + k0 + q8),
                (las_p)((char*)&Bs[0][0] + (size_t)(w * 128 + it * 64) * 16),
                16, 0, 0);
        }
        __syncthreads();
        bf16x8 af[4], bf[4];
        #pragma unroll
        for (int i = 0; i < 4; i++) af[i] = *(const bf16x8*)&As[wm + i*16 + l15][quad * 8];
        #pragma unroll
        for (int j = 0; j < 4; j++) bf[j] = *(const bf16x8*)&Bs[wn + j*16 + l15][quad * 8];
        #pragma unroll
        for (int i = 0; i < 4; i++)
            #pragma unroll
            for (int j = 0; j < 4; j++)
                acc[i][j] = __builtin_amdgcn_mfma_f32_16x16x32_bf16(af[i], bf[j], acc[i][j], 0, 0, 0);
        __syncthreads();
    }

    #pragma unroll
    for (int i = 0; i < 4; i++)
        #pragma unroll
        for (int j = 0; j < 4; j++)
            #pragma unroll
            for (int r = 0; r < 4; r++) {
                size_t idx = (size_t)(row0 + wm + i*16 + quad*4 + r) * N + col0 + wn + j*16 + l15;
                if (BF16OUT) ((unsigned short*)Cv)[idx] = f2b(acc[i][j][r]);
                else         ((float*)Cv)[idx] = acc[i][j][r];
            }
}

// ---------- RoPE on Q,K region (cols 0..2559), in place --------------------
__global__ __launch_bounds__(256)
void rope_kernel(unsigned short* __restrict__ qkv, const float* __restrict__ freqs) {
    int p = blockIdx.x * 256 + threadIdx.x;
    int m = p / 1280;
    int cp = p - m * 1280;
    int col = cp * 2;
    int s = m & (S_ - 1);
    int d = col & (D_ - 1);
    unsigned short* ptr = qkv + (size_t)m * NQKV + col;
    ushort2 uv = *(ushort2*)ptr;
    float xr = b2f(uv.x), xi = b2f(uv.y);
    float cs = freqs[s * 128 + d], sn = freqs[s * 128 + d + 1];
    ushort2 ov;
    ov.x = f2b(xr * cs - xi * sn);
    ov.y = f2b(xr * sn + xi * cs);
    *(ushort2*)ptr = ov;
}

// ---------- transpose V region -> vT[(b*512 + kvcol)][s] -------------------
__global__ __launch_bounds__(256)
void v_transpose(const unsigned short* __restrict__ qkv, unsigned short* __restrict__ vT) {
    __shared__ unsigned short tile[32][34];
    int tx = threadIdx.x & 31, ty = threadIdx.x >> 5;
    int s0 = blockIdx.x * 32;
    int c0 = blockIdx.y * 32;
    int b  = blockIdx.z;
    #pragma unroll
    for (int j = 0; j < 4; j++)
        tile[ty + j*8][tx] = qkv[(size_t)(b*2048 + s0 + ty + j*8) * NQKV + 2560 + c0 + tx];
    __syncthreads();
    #pragma unroll
    for (int j = 0; j < 4; j++)
        vT[(size_t)(b*512 + c0 + ty + j*8) * 2048 + s0 + tx] = tile[tx][ty + j*8];
}

// ---------- MFMA flash attention, S^T formulation --------------------------
// S^T = K·Q^T via mfma(K_frag, Q_frag): C-layout lane = q-col (l15),
// rows = s (quad*4+reg, s-permuted). Softmax stats are per-lane scalars
// (15 in-reg ops + shfl_xor 16/32). The lane's 16 P values pack directly
// into the PV B-operand (lane = q, k = s) -> NO LDS round-trip for P.
// PV = mfma(V^T_frag, P_frag) accumulates O^T (lane = q, rows = d).
// K s-rows permuted at frag load: row(j,l15) = (j>=2)*32 + (l15>>2)*8
// + (j&1)*4 + (l15&3), so P packs as {p[0][0..3],p[1][0..3]} per K=32 frag.
// K/V double-buffered via global_load_lds (async), XOR-swizzled as r4.
__global__ __launch_bounds__(256)
void attn_mfma(const unsigned short* __restrict__ qkv,
               const unsigned short* __restrict__ vT,
               unsigned short* __restrict__ ao) {
    __shared__ unsigned short Ks[2][64 * 128];   // 16KB per buffer, swizzled
    __shared__ unsigned short Vt[2][128 * 64];   // 16KB per buffer, swizzled

    int tid  = threadIdx.x;
    int lane = tid & 63, w = tid >> 6;
    int quad = lane >> 4, l15 = lane & 15;
    int qt = blockIdx.x, h = blockIdx.y, b = blockIdx.z;
    int hk = h >> 2;
    int q0 = qt * 64;
    const float scale = 0.08838834764831845f;   // 1/sqrt(128)

    // Q as B-frag: lane = q-row (l15 within wave's 16), k = k4*32 + quad*8
    bf16x8 aq[4];
    {
        const unsigned short* qrow = qkv + (size_t)(b*2048 + q0 + w*16 + l15) * NQKV + h*128;
        #pragma unroll
        for (int k4 = 0; k4 < 4; k4++)
            aq[k4] = *(const bf16x8*)(qrow + k4*32 + quad*8);
    }

    // Loop-invariant LDS frag offsets (u16 element offsets within a buffer)
    int koff[4][4];   // [j][k4]: K A-frag, s-permuted row, XOR-swizzled chunk
    #pragma unroll
    for (int j = 0; j < 4; j++) {
        int row = ((j >> 1) * 32) + ((l15 >> 2) * 8) + ((j & 1) * 4) + (l15 & 3);
        #pragma unroll
        for (int k4 = 0; k4 < 4; k4++) {
            int slot = (k4 * 4 + quad) ^ (row & 15);
            koff[j][k4] = (row * 16 + slot) * 8;
        }
    }
    int voff[8][2];   // [jn][shalf]: V^T A-frag
    #pragma unroll
    for (int jn = 0; jn < 8; jn++) {
        int row = jn * 16 + l15;
        #pragma unroll
        for (int sh = 0; sh < 2; sh++) {
            int slot = (sh * 4 + quad) ^ (row & 7);
            voff[jn][sh] = (row * 8 + slot) * 8;
        }
    }

    const unsigned short* kb0 = qkv + (size_t)(b*2048) * NQKV + 2048 + hk*128;
    const unsigned short* vb0 = vT + (size_t)(b*512 + hk*128) * 2048;

    auto stage = [&](int kt, int buf) {
        #pragma unroll
        for (int it = 0; it < 4; it++) {
            int s = w * 256 + it * 64 + lane;
            int r = s >> 4, qp = s & 15;
            int q = qp ^ (r & 15);
            __builtin_amdgcn_global_load_lds(
                (gas_p)(kb0 + (size_t)(kt*64 + r) * NQKV + q * 8),
                (las_p)((char*)&Ks[buf][0] + (w * 256 + it * 64) * 16),
                16, 0, 0);
        }
        #pragma unroll
        for (int it = 0; it < 4; it++) {
            int s = w * 256 + it * 64 + lane;
            int r = s >> 3, qp = s & 7;
            int q = qp ^ (r & 7);
            __builtin_amdgcn_global_load_lds(
                (gas_p)(vb0 + (size_t)r * 2048 + kt*64 + q * 8),
                (las_p)((char*)&Vt[buf][0] + (w * 256 + it * 64) * 16),
                16, 0, 0);
        }
    };

    f32x4 o_acc[8];                  // O^T: lane = q (l15), rows d = quad*4+r
    const f32x4 zf = {0.f, 0.f, 0.f, 0.f};
    #pragma unroll
    for (int jn = 0; jn < 8; jn++) o_acc[jn] = zf;
    float m_i = -1e30f, l_i = 0.f;   // per-lane scalars (one q-row per lane)
    const int qglob = q0 + w*16 + l15;

    stage(0, 0);
    for (int kt = 0; kt <= qt; kt++) {
        int cur = kt & 1;
        __syncthreads();                       // tile kt landed
        if (kt < qt) stage(kt + 1, cur ^ 1);   // async prefetch during compute

        // ---- S^T = K·Q^T : 4 j-tiles (s-chunks of 16, permuted) ----
        f32x4 s_acc[4];
        #pragma unroll
        for (int j = 0; j < 4; j++) {
            s_acc[j] = zf;
            #pragma unroll
            for (int k4 = 0; k4 < 4; k4++) {
                bf16x8 ak = *(const bf16x8*)&Ks[cur][koff[j][k4]];
                s_acc[j] = __builtin_amdgcn_mfma_f32_16x16x32_bf16(ak, aq[k4], s_acc[j], 0, 0, 0);
            }
        }

        // ---- scale + mask (lane's 16 values, s = (j>=2)*32+quad*8+(j&1)*4+r)
        float sv[4][4];
        #pragma unroll
        for (int j = 0; j < 4; j++)
            #pragma unroll
            for (int r = 0; r < 4; r++)
                sv[j][r] = s_acc[j][r] * scale;
        if (kt == qt) {
            #pragma unroll
            for (int j = 0; j < 4; j++)
                #pragma unroll
                for (int r = 0; r < 4; r++) {
                    int sloc = ((j >> 1) * 32) + quad*8 + ((j & 1) * 4) + r;
                    if (kt*64 + sloc > qglob) sv[j][r] = -1e30f;
                }
        }

        // ---- online softmax: per-lane scalar stats ----
        float mx = sv[0][0];
        #pragma unroll
        for (int j = 0; j < 4; j++)
            #pragma unroll
            for (int r = 0; r < 4; r++) mx = fmaxf(mx, sv[j][r]);
        mx = fmaxf(mx, __shfl_xor(mx, 16));
        mx = fmaxf(mx, __shfl_xor(mx, 32));
        float mnew = fmaxf(m_i, mx);
        float alpha = __expf(m_i - mnew);
        float p[4][4], rs = 0.f;
        #pragma unroll
        for (int j = 0; j < 4; j++)
            #pragma unroll
            for (int r = 0; r < 4; r++) {
                p[j][r] = __expf(sv[j][r] - mnew);
                rs += p[j][r];
            }
        rs += __shfl_xor(rs, 16);
        rs += __shfl_xor(rs, 32);
        l_i = l_i * alpha + rs;
        m_i = mnew;
        #pragma unroll
        for (int jn = 0; jn < 8; jn++)
            #pragma unroll
            for (int r = 0; r < 4; r++) o_acc[jn][r] *= alpha;

        // ---- pack P into PV B-frags (lane = q, k = s = quad*8 + elem) ----
        bf16x8 pp0, pp1;
        #pragma unroll
        for (int r = 0; r < 4; r++) {
            pp0[r]     = (short)f2b(p[0][r]);
            pp0[r + 4] = (short)f2b(p[1][r]);
            pp1[r]     = (short)f2b(p[2][r]);
            pp1[r + 4] = (short)f2b(p[3][r]);
        }

        // ---- PV: O^T += V^T · P^T ----
        #pragma unroll
        for (int jn = 0; jn < 8; jn++) {
            bf16x8 av0 = *(const bf16x8*)&Vt[cur][voff[jn][0]];
            bf16x8 av1 = *(const bf16x8*)&Vt[cur][voff[jn][1]];
            o_acc[jn] = __builtin_amdgcn_mfma_f32_16x16x32_bf16(av0, pp0, o_acc[jn], 0, 0, 0);
            o_acc[jn] = __builtin_amdgcn_mfma_f32_16x16x32_bf16(av1, pp1, o_acc[jn], 0, 0, 0);
        }
    }

    // ---- epilogue: lane = q-row, d = jn*16 + quad*4 + r ----
    float inv = 1.f / l_i;
    size_t base = (size_t)(b*2048 + qglob) * 2048 + h*128;
    #pragma unroll
    for (int jn = 0; jn < 8; jn++) {
        ushort4 ov;
        ov.x = f2b(o_acc[jn][0] * inv);
        ov.y = f2b(o_acc[jn][1] * inv);
        ov.z = f2b(o_acc[jn][2] * inv);
        ov.w = f2b(o_acc[jn][3] * inv);
        *(ushort4*)(ao + base + jn*16 + quad*4) = ov;
    }
}

// ---------- launch ---------------------------------------------------------
extern "C" void kernel_launch(void* const* d_in, const int* in_sizes, int n_in,
                              void* d_out, int out_size, void* d_ws, size_t ws_size,
                              hipStream_t stream) {
    const float* x     = (const float*)d_in[0];
    const float* freqs = (const float*)d_in[1];
    const float* wq    = (const float*)d_in[2];
    const float* wk    = (const float*)d_in[3];
    const float* wv    = (const float*)d_in[4];
    const float* wo    = (const float*)d_in[5];
    float* out = (float*)d_out;

    char* ws = (char*)d_ws;
    unsigned short* xbf    = (unsigned short*)(ws);                  // 16MB
    unsigned short* aobuf  = (unsigned short*)(ws);                  // alias (xbf dead)
    unsigned short* wqkvT  = (unsigned short*)(ws + (16u<<20));      // 12MB
    unsigned short* woT    = (unsigned short*)(ws + (28u<<20));      // 8MB
    unsigned short* qkvbuf = (unsigned short*)(ws + (36u<<20));      // 24MB
    unsigned short* vTbuf  = (unsigned short*)(ws + (60u<<20));      // 4MB

    dim3 blk(256);
    convert_x<<<8192, blk, 0, stream>>>(x, xbf);
    convert_w_t<<<dim3(64, 64), blk, 0, stream>>>(wq, 2048, wqkvT, 0);
    convert_w_t<<<dim3(16, 64), blk, 0, stream>>>(wk,  512, wqkvT, 2048);
    convert_w_t<<<dim3(16, 64), blk, 0, stream>>>(wv,  512, wqkvT, 2560);
    convert_w_t<<<dim3(64, 64), blk, 0, stream>>>(wo, 2048, woT, 0);

    gemm_bt<true><<<dim3(NQKV/128, M_/128), blk, 0, stream>>>(xbf, wqkvT, qkvbuf, NQKV);
    rope_kernel<<<20480, blk, 0, stream>>>(qkvbuf, freqs);
    v_transpose<<<dim3(64, 16, 2), blk, 0, stream>>>(qkvbuf, vTbuf);
    attn_mfma<<<dim3(32, 16, 2), blk, 0, stream>>>(qkvbuf, vTbuf, aobuf);
    gemm_bt<false><<<dim3(2048/128, M_/128), blk, 0, stream>>>(aobuf, woT, out, 2048);
}

// Round 6
// 355.847 us; speedup vs baseline: 1.5454x; 1.0447x over previous
//
#include <hip/hip_runtime.h>
#include <hip/hip_bf16.h>

#define B_   2
#define S_   2048
#define HID_ 2048
#define H_   16
#define KVH_ 4
#define D_   128
#define M_   4096
#define NQKV 3072

typedef __attribute__((ext_vector_type(8))) short bf16x8;   // 8 bf16 = 4 VGPR
typedef __attribute__((ext_vector_type(4))) float f32x4;
typedef const __attribute__((address_space(1))) unsigned int* gas_p;
typedef __attribute__((address_space(3))) unsigned int* las_p;

__device__ __forceinline__ unsigned short f2b(float f) {
    __hip_bfloat16 h = __float2bfloat16(f);
    return *reinterpret_cast<unsigned short*>(&h);
}
__device__ __forceinline__ float b2f(unsigned short u) {
    __hip_bfloat16 h;
    *reinterpret_cast<unsigned short*>(&h) = u;
    return __bfloat162float(h);
}

// ---------- convert x: fp32 -> bf16 ----------------------------------------
__global__ __launch_bounds__(256)
void convert_x(const float* __restrict__ x, unsigned short* __restrict__ xb) {
    int i = (blockIdx.x * 256 + threadIdx.x) * 4;
    float4 v = *(const float4*)(x + i);
    ushort4 o;
    o.x = f2b(v.x); o.y = f2b(v.y); o.z = f2b(v.z); o.w = f2b(v.w);
    *(ushort4*)(xb + i) = o;
}

// ---------- convert + transpose weight: w[2048][N] fp32 -> wt[n][k] bf16 ---
__global__ __launch_bounds__(256)
void convert_w_t(const float* __restrict__ w, int N,
                 unsigned short* __restrict__ wt, int nbase) {
    __shared__ float tile[32][33];
    int tx = threadIdx.x & 31, ty = threadIdx.x >> 5;
    int n0 = blockIdx.x * 32, k0 = blockIdx.y * 32;
    #pragma unroll
    for (int j = 0; j < 4; j++)
        tile[ty + j*8][tx] = w[(size_t)(k0 + ty + j*8) * N + n0 + tx];
    __syncthreads();
    #pragma unroll
    for (int j = 0; j < 4; j++)
        wt[(size_t)(nbase + n0 + ty + j*8) * 2048 + k0 + tx] = f2b(tile[tx][ty + j*8]);
}

// ---------- MFMA GEMM (m97 structure): C = A[M][2048] * BT[N][2048]^T ------
template<bool BF16OUT>
__global__ __launch_bounds__(256)
void gemm_bt(const unsigned short* __restrict__ A,
             const unsigned short* __restrict__ BT,
             void* __restrict__ Cv, int N) {
    __shared__ unsigned short As[128][32];
    __shared__ unsigned short Bs[128][32];

    int tid  = threadIdx.x;
    int lane = tid & 63, w = tid >> 6;
    int quad = lane >> 4, l15 = lane & 15;
    int row0 = blockIdx.y * 128, col0 = blockIdx.x * 128;
    int wm = (w & 1) * 64, wn = (w >> 1) * 64;

    f32x4 acc[4][4];
    const f32x4 zf = {0.f, 0.f, 0.f, 0.f};
    #pragma unroll
    for (int i = 0; i < 4; i++)
        #pragma unroll
        for (int j = 0; j < 4; j++) acc[i][j] = zf;

    const unsigned short* Arow = A  + (size_t)row0 * 2048;
    const unsigned short* Brow = BT + (size_t)col0 * 2048;

    for (int k0 = 0; k0 < 2048; k0 += 32) {
        #pragma unroll
        for (int it = 0; it < 2; it++) {
            int c = w * 128 + it * 64 + lane;
            int r = c >> 2, q8 = (c & 3) * 8;
            __builtin_amdgcn_global_load_lds(
                (gas_p)(Arow + (size_t)r * 2048 + k0 + q8),
                (las_p)((char*)&As[0][0] + (size_t)(w * 128 + it * 64) * 16),
                16, 0, 0);
            __builtin_amdgcn_global_load_lds(
                (gas_p)(Brow + (size_t)r * 2048 + k0 + q8),
                (las_p)((char*)&Bs[0][0] + (size_t)(w * 128 + it * 64) * 16),
                16, 0, 0);
        }
        __syncthreads();
        bf16x8 af[4], bf[4];
        #pragma unroll
        for (int i = 0; i < 4; i++) af[i] = *(const bf16x8*)&As[wm + i*16 + l15][quad * 8];
        #pragma unroll
        for (int j = 0; j < 4; j++) bf[j] = *(const bf16x8*)&Bs[wn + j*16 + l15][quad * 8];
        #pragma unroll
        for (int i = 0; i < 4; i++)
            #pragma unroll
            for (int j = 0; j < 4; j++)
                acc[i][j] = __builtin_amdgcn_mfma_f32_16x16x32_bf16(af[i], bf[j], acc[i][j], 0, 0, 0);
        __syncthreads();
    }

    #pragma unroll
    for (int i = 0; i < 4; i++)
        #pragma unroll
        for (int j = 0; j < 4; j++)
            #pragma unroll
            for (int r = 0; r < 4; r++) {
                size_t idx = (size_t)(row0 + wm + i*16 + quad*4 + r) * N + col0 + wn + j*16 + l15;
                if (BF16OUT) ((unsigned short*)Cv)[idx] = f2b(acc[i][j][r]);
                else         ((float*)Cv)[idx] = acc[i][j][r];
            }
}

// ---------- RoPE on Q,K region (cols 0..2559), in place --------------------
__global__ __launch_bounds__(256)
void rope_kernel(unsigned short* __restrict__ qkv, const float* __restrict__ freqs) {
    int p = blockIdx.x * 256 + threadIdx.x;
    int m = p / 1280;
    int cp = p - m * 1280;
    int col = cp * 2;
    int s = m & (S_ - 1);
    int d = col & (D_ - 1);
    unsigned short* ptr = qkv + (size_t)m * NQKV + col;
    ushort2 uv = *(ushort2*)ptr;
    float xr = b2f(uv.x), xi = b2f(uv.y);
    float cs = freqs[s * 128 + d], sn = freqs[s * 128 + d + 1];
    ushort2 ov;
    ov.x = f2b(xr * cs - xi * sn);
    ov.y = f2b(xr * sn + xi * cs);
    *(ushort2*)ptr = ov;
}

// ---------- transpose V region -> vT[(b*512 + kvcol)][s] -------------------
__global__ __launch_bounds__(256)
void v_transpose(const unsigned short* __restrict__ qkv, unsigned short* __restrict__ vT) {
    __shared__ unsigned short tile[32][34];
    int tx = threadIdx.x & 31, ty = threadIdx.x >> 5;
    int s0 = blockIdx.x * 32;
    int c0 = blockIdx.y * 32;
    int b  = blockIdx.z;
    #pragma unroll
    for (int j = 0; j < 4; j++)
        tile[ty + j*8][tx] = qkv[(size_t)(b*2048 + s0 + ty + j*8) * NQKV + 2560 + c0 + tx];
    __syncthreads();
    #pragma unroll
    for (int j = 0; j < 4; j++)
        vT[(size_t)(b*512 + c0 + ty + j*8) * 2048 + s0 + tx] = tile[tx][ty + j*8];
}

// ---------- MFMA flash attention, S^T formulation, 32KB LDS ----------------
// SINGLE-buffered K and V with a two-barrier schedule that stays async:
//   [barrier A] (drains K(kt) DMA; V buf free since all PV(kt-1) done)
//   issue V(kt) DMA -> QK^T + softmax (~600cyc, hides V latency)
//   [barrier B] (drains V(kt); K buf free since all QK(kt) reads done)
//   issue K(kt+1) DMA -> PV (hides part of K latency)
// 32KB LDS + 92 VGPR -> 5 blocks (20 waves)/CU vs 2 blocks before: latency
// hiding by residency instead of per-wave pipelining.
// Softmax: per-tile cross-lane reduce for MAX only (xor16+xor32); the SUM
// is accumulated per-lane (alpha is quad-uniform) and reduced once at the
// end -> 2 fewer dependent bpermutes per tile on the critical path.
__global__ __launch_bounds__(256)
void attn_mfma(const unsigned short* __restrict__ qkv,
               const unsigned short* __restrict__ vT,
               unsigned short* __restrict__ ao) {
    __shared__ unsigned short Ks[64 * 128];   // 16KB, XOR-swizzled
    __shared__ unsigned short Vt[128 * 64];   // 16KB, XOR-swizzled

    int tid  = threadIdx.x;
    int lane = tid & 63, w = tid >> 6;
    int quad = lane >> 4, l15 = lane & 15;
    int qt = 31 - blockIdx.x;                 // heavy blocks dispatch first
    int h = blockIdx.y, b = blockIdx.z;
    int hk = h >> 2;
    int q0 = qt * 64;
    const float scale = 0.08838834764831845f;   // 1/sqrt(128)

    // Q as B-frag: lane = q-row (l15 within wave's 16), k = k4*32 + quad*8
    bf16x8 aq[4];
    {
        const unsigned short* qrow = qkv + (size_t)(b*2048 + q0 + w*16 + l15) * NQKV + h*128;
        #pragma unroll
        for (int k4 = 0; k4 < 4; k4++)
            aq[k4] = *(const bf16x8*)(qrow + k4*32 + quad*8);
    }

    // Loop-invariant LDS frag offsets (u16 element offsets)
    int koff[4][4];   // [j][k4]: K A-frag, s-permuted row, XOR-swizzled chunk
    #pragma unroll
    for (int j = 0; j < 4; j++) {
        int row = ((j >> 1) * 32) + ((l15 >> 2) * 8) + ((j & 1) * 4) + (l15 & 3);
        #pragma unroll
        for (int k4 = 0; k4 < 4; k4++) {
            int slot = (k4 * 4 + quad) ^ (row & 15);
            koff[j][k4] = (row * 16 + slot) * 8;
        }
    }
    int voff[8][2];   // [jn][shalf]: V^T A-frag
    #pragma unroll
    for (int jn = 0; jn < 8; jn++) {
        int row = jn * 16 + l15;
        #pragma unroll
        for (int sh = 0; sh < 2; sh++) {
            int slot = (sh * 4 + quad) ^ (row & 7);
            voff[jn][sh] = (row * 8 + slot) * 8;
        }
    }

    const unsigned short* kb0 = qkv + (size_t)(b*2048) * NQKV + 2048 + hk*128;
    const unsigned short* vb0 = vT + (size_t)(b*512 + hk*128) * 2048;

    auto stage_k = [&](int kt) {
        #pragma unroll
        for (int it = 0; it < 4; it++) {
            int s = w * 256 + it * 64 + lane;
            int r = s >> 4, qp = s & 15;
            int q = qp ^ (r & 15);
            __builtin_amdgcn_global_load_lds(
                (gas_p)(kb0 + (size_t)(kt*64 + r) * NQKV + q * 8),
                (las_p)((char*)&Ks[0] + (w * 256 + it * 64) * 16),
                16, 0, 0);
        }
    };
    auto stage_v = [&](int kt) {
        #pragma unroll
        for (int it = 0; it < 4; it++) {
            int s = w * 256 + it * 64 + lane;
            int r = s >> 3, qp = s & 7;
            int q = qp ^ (r & 7);
            __builtin_amdgcn_global_load_lds(
                (gas_p)(vb0 + (size_t)r * 2048 + kt*64 + q * 8),
                (las_p)((char*)&Vt[0] + (w * 256 + it * 64) * 16),
                16, 0, 0);
        }
    };

    f32x4 o_acc[8];                  // O^T: lane = q (l15), rows d = quad*4+r
    const f32x4 zf = {0.f, 0.f, 0.f, 0.f};
    #pragma unroll
    for (int jn = 0; jn < 8; jn++) o_acc[jn] = zf;
    float m_i = -1e30f, l_i = 0.f;   // m quad-uniform; l per-lane PARTIAL
    const int qglob = q0 + w*16 + l15;

    stage_k(0);
    for (int kt = 0; kt <= qt; kt++) {
        __syncthreads();             // A: K(kt) landed; V buffer free
        stage_v(kt);                 // async during QK+softmax

        // ---- S^T = K·Q^T : 4 j-tiles (s-chunks of 16, permuted) ----
        f32x4 s_acc[4];
        #pragma unroll
        for (int j = 0; j < 4; j++) {
            s_acc[j] = zf;
            #pragma unroll
            for (int k4 = 0; k4 < 4; k4++) {
                bf16x8 ak = *(const bf16x8*)&Ks[koff[j][k4]];
                s_acc[j] = __builtin_amdgcn_mfma_f32_16x16x32_bf16(ak, aq[k4], s_acc[j], 0, 0, 0);
            }
        }

        // ---- scale + mask ----
        float sv[4][4];
        #pragma unroll
        for (int j = 0; j < 4; j++)
            #pragma unroll
            for (int r = 0; r < 4; r++)
                sv[j][r] = s_acc[j][r] * scale;
        if (kt == qt) {
            #pragma unroll
            for (int j = 0; j < 4; j++)
                #pragma unroll
                for (int r = 0; r < 4; r++) {
                    int sloc = ((j >> 1) * 32) + quad*8 + ((j & 1) * 4) + r;
                    if (kt*64 + sloc > qglob) sv[j][r] = -1e30f;
                }
        }

        // ---- online softmax: cross-lane reduce for max only ----
        float mx = sv[0][0];
        #pragma unroll
        for (int j = 0; j < 4; j++)
            #pragma unroll
            for (int r = 0; r < 4; r++) mx = fmaxf(mx, sv[j][r]);
        mx = fmaxf(mx, __shfl_xor(mx, 16));
        mx = fmaxf(mx, __shfl_xor(mx, 32));
        float mnew = fmaxf(m_i, mx);
        float alpha = __expf(m_i - mnew);
        float p[4][4], rs = 0.f;
        #pragma unroll
        for (int j = 0; j < 4; j++)
            #pragma unroll
            for (int r = 0; r < 4; r++) {
                p[j][r] = __expf(sv[j][r] - mnew);
                rs += p[j][r];
            }
        l_i = l_i * alpha + rs;      // per-lane partial; reduced after loop
        m_i = mnew;
        #pragma unroll
        for (int jn = 0; jn < 8; jn++)
            #pragma unroll
            for (int r = 0; r < 4; r++) o_acc[jn][r] *= alpha;

        // ---- pack P into PV B-frags (lane = q, k = s = quad*8 + elem) ----
        bf16x8 pp0, pp1;
        #pragma unroll
        for (int r = 0; r < 4; r++) {
            pp0[r]     = (short)f2b(p[0][r]);
            pp0[r + 4] = (short)f2b(p[1][r]);
            pp1[r]     = (short)f2b(p[2][r]);
            pp1[r + 4] = (short)f2b(p[3][r]);
        }

        __syncthreads();             // B: V(kt) landed; K buffer free
        if (kt < qt) stage_k(kt + 1);   // async during PV

        // ---- PV: O^T += V^T · P^T ----
        #pragma unroll
        for (int jn = 0; jn < 8; jn++) {
            bf16x8 av0 = *(const bf16x8*)&Vt[voff[jn][0]];
            bf16x8 av1 = *(const bf16x8*)&Vt[voff[jn][1]];
            o_acc[jn] = __builtin_amdgcn_mfma_f32_16x16x32_bf16(av0, pp0, o_acc[jn], 0, 0, 0);
            o_acc[jn] = __builtin_amdgcn_mfma_f32_16x16x32_bf16(av1, pp1, o_acc[jn], 0, 0, 0);
        }
    }

    // ---- final l reduction over the 4 quads of each q-row ----
    float lt = l_i;
    lt += __shfl_xor(lt, 16);
    lt += __shfl_xor(lt, 32);
    float inv = 1.f / lt;

    size_t base = (size_t)(b*2048 + qglob) * 2048 + h*128;
    #pragma unroll
    for (int jn = 0; jn < 8; jn++) {
        ushort4 ov;
        ov.x = f2b(o_acc[jn][0] * inv);
        ov.y = f2b(o_acc[jn][1] * inv);
        ov.z = f2b(o_acc[jn][2] * inv);
        ov.w = f2b(o_acc[jn][3] * inv);
        *(ushort4*)(ao + base + jn*16 + quad*4) = ov;
    }
}

// ---------- launch ---------------------------------------------------------
extern "C" void kernel_launch(void* const* d_in, const int* in_sizes, int n_in,
                              void* d_out, int out_size, void* d_ws, size_t ws_size,
                              hipStream_t stream) {
    const float* x     = (const float*)d_in[0];
    const float* freqs = (const float*)d_in[1];
    const float* wq    = (const float*)d_in[2];
    const float* wk    = (const float*)d_in[3];
    const float* wv    = (const float*)d_in[4];
    const float* wo    = (const float*)d_in[5];
    float* out = (float*)d_out;

    char* ws = (char*)d_ws;
    unsigned short* xbf    = (unsigned short*)(ws);                  // 16MB
    unsigned short* aobuf  = (unsigned short*)(ws);                  // alias (xbf dead)
    unsigned short* wqkvT  = (unsigned short*)(ws + (16u<<20));      // 12MB
    unsigned short* woT    = (unsigned short*)(ws + (28u<<20));      // 8MB
    unsigned short* qkvbuf = (unsigned short*)(ws + (36u<<20));      // 24MB
    unsigned short* vTbuf  = (unsigned short*)(ws + (60u<<20));      // 4MB

    dim3 blk(256);
    convert_x<<<8192, blk, 0, stream>>>(x, xbf);
    convert_w_t<<<dim3(64, 64), blk, 0, stream>>>(wq, 2048, wqkvT, 0);
    convert_w_t<<<dim3(16, 64), blk, 0, stream>>>(wk,  512, wqkvT, 2048);
    convert_w_t<<<dim3(16, 64), blk, 0, stream>>>(wv,  512, wqkvT, 2560);
    convert_w_t<<<dim3(64, 64), blk, 0, stream>>>(wo, 2048, woT, 0);

    gemm_bt<true><<<dim3(NQKV/128, M_/128), blk, 0, stream>>>(xbf, wqkvT, qkvbuf, NQKV);
    rope_kernel<<<20480, blk, 0, stream>>>(qkvbuf, freqs);
    v_transpose<<<dim3(64, 16, 2), blk, 0, stream>>>(qkvbuf, vTbuf);
    attn_mfma<<<dim3(32, 16, 2), blk, 0, stream>>>(qkvbuf, vTbuf, aobuf);
    gemm_bt<false><<<dim3(2048/128, M_/128), blk, 0, stream>>>(aobuf, woT, out, 2048);
}

// Round 7
// 353.814 us; speedup vs baseline: 1.5542x; 1.0057x over previous
//
#include <hip/hip_runtime.h>
#include <hip/hip_bf16.h>

#define B_   2
#define S_   2048
#define HID_ 2048
#define H_   16
#define KVH_ 4
#define D_   128
#define M_   4096
#define NQKV 3072

typedef __attribute__((ext_vector_type(8))) short bf16x8;   // 8 bf16 = 4 VGPR
typedef __attribute__((ext_vector_type(4))) float f32x4;
typedef const __attribute__((address_space(1))) unsigned int* gas_p;
typedef __attribute__((address_space(3))) unsigned int* las_p;

__device__ __forceinline__ unsigned short f2b(float f) {
    __hip_bfloat16 h = __float2bfloat16(f);
    return *reinterpret_cast<unsigned short*>(&h);
}
__device__ __forceinline__ float b2f(unsigned short u) {
    __hip_bfloat16 h;
    *reinterpret_cast<unsigned short*>(&h) = u;
    return __bfloat162float(h);
}

// ---------- convert x: fp32 -> bf16 ----------------------------------------
__global__ __launch_bounds__(256)
void convert_x(const float* __restrict__ x, unsigned short* __restrict__ xb) {
    int i = (blockIdx.x * 256 + threadIdx.x) * 4;
    float4 v = *(const float4*)(x + i);
    ushort4 o;
    o.x = f2b(v.x); o.y = f2b(v.y); o.z = f2b(v.z); o.w = f2b(v.w);
    *(ushort4*)(xb + i) = o;
}

// ---------- convert + transpose weight: w[2048][N] fp32 -> wt[n][k] bf16 ---
__global__ __launch_bounds__(256)
void convert_w_t(const float* __restrict__ w, int N,
                 unsigned short* __restrict__ wt, int nbase) {
    __shared__ float tile[32][33];
    int tx = threadIdx.x & 31, ty = threadIdx.x >> 5;
    int n0 = blockIdx.x * 32, k0 = blockIdx.y * 32;
    #pragma unroll
    for (int j = 0; j < 4; j++)
        tile[ty + j*8][tx] = w[(size_t)(k0 + ty + j*8) * N + n0 + tx];
    __syncthreads();
    #pragma unroll
    for (int j = 0; j < 4; j++)
        wt[(size_t)(nbase + n0 + ty + j*8) * 2048 + k0 + tx] = f2b(tile[tx][ty + j*8]);
}

// ---------- MFMA GEMM (m97 structure): C = A[M][2048] * BT[N][2048]^T ------
template<bool BF16OUT>
__global__ __launch_bounds__(256)
void gemm_bt(const unsigned short* __restrict__ A,
             const unsigned short* __restrict__ BT,
             void* __restrict__ Cv, int N) {
    __shared__ unsigned short As[128][32];
    __shared__ unsigned short Bs[128][32];

    int tid  = threadIdx.x;
    int lane = tid & 63, w = tid >> 6;
    int quad = lane >> 4, l15 = lane & 15;
    int row0 = blockIdx.y * 128, col0 = blockIdx.x * 128;
    int wm = (w & 1) * 64, wn = (w >> 1) * 64;

    f32x4 acc[4][4];
    const f32x4 zf = {0.f, 0.f, 0.f, 0.f};
    #pragma unroll
    for (int i = 0; i < 4; i++)
        #pragma unroll
        for (int j = 0; j < 4; j++) acc[i][j] = zf;

    const unsigned short* Arow = A  + (size_t)row0 * 2048;
    const unsigned short* Brow = BT + (size_t)col0 * 2048;

    for (int k0 = 0; k0 < 2048; k0 += 32) {
        #pragma unroll
        for (int it = 0; it < 2; it++) {
            int c = w * 128 + it * 64 + lane;
            int r = c >> 2, q8 = (c & 3) * 8;
            __builtin_amdgcn_global_load_lds(
                (gas_p)(Arow + (size_t)r * 2048 + k0 + q8),
                (las_p)((char*)&As[0][0] + (size_t)(w * 128 + it * 64) * 16),
                16, 0, 0);
            __builtin_amdgcn_global_load_lds(
                (gas_p)(Brow + (size_t)r * 2048 + k0 + q8),
                (las_p)((char*)&Bs[0][0] + (size_t)(w * 128 + it * 64) * 16),
                16, 0, 0);
        }
        __syncthreads();
        bf16x8 af[4], bf[4];
        #pragma unroll
        for (int i = 0; i < 4; i++) af[i] = *(const bf16x8*)&As[wm + i*16 + l15][quad * 8];
        #pragma unroll
        for (int j = 0; j < 4; j++) bf[j] = *(const bf16x8*)&Bs[wn + j*16 + l15][quad * 8];
        #pragma unroll
        for (int i = 0; i < 4; i++)
            #pragma unroll
            for (int j = 0; j < 4; j++)
                acc[i][j] = __builtin_amdgcn_mfma_f32_16x16x32_bf16(af[i], bf[j], acc[i][j], 0, 0, 0);
        __syncthreads();
    }

    #pragma unroll
    for (int i = 0; i < 4; i++)
        #pragma unroll
        for (int j = 0; j < 4; j++)
            #pragma unroll
            for (int r = 0; r < 4; r++) {
                size_t idx = (size_t)(row0 + wm + i*16 + quad*4 + r) * N + col0 + wn + j*16 + l15;
                if (BF16OUT) ((unsigned short*)Cv)[idx] = f2b(acc[i][j][r]);
                else         ((float*)Cv)[idx] = acc[i][j][r];
            }
}

// ---------- RoPE on Q,K region (cols 0..2559), in place --------------------
__global__ __launch_bounds__(256)
void rope_kernel(unsigned short* __restrict__ qkv, const float* __restrict__ freqs) {
    int p = blockIdx.x * 256 + threadIdx.x;
    int m = p / 1280;
    int cp = p - m * 1280;
    int col = cp * 2;
    int s = m & (S_ - 1);
    int d = col & (D_ - 1);
    unsigned short* ptr = qkv + (size_t)m * NQKV + col;
    ushort2 uv = *(ushort2*)ptr;
    float xr = b2f(uv.x), xi = b2f(uv.y);
    float cs = freqs[s * 128 + d], sn = freqs[s * 128 + d + 1];
    ushort2 ov;
    ov.x = f2b(xr * cs - xi * sn);
    ov.y = f2b(xr * sn + xi * cs);
    *(ushort2*)ptr = ov;
}

// ---------- transpose V region -> vT[(b*512 + kvcol)][s] -------------------
__global__ __launch_bounds__(256)
void v_transpose(const unsigned short* __restrict__ qkv, unsigned short* __restrict__ vT) {
    __shared__ unsigned short tile[32][34];
    int tx = threadIdx.x & 31, ty = threadIdx.x >> 5;
    int s0 = blockIdx.x * 32;
    int c0 = blockIdx.y * 32;
    int b  = blockIdx.z;
    #pragma unroll
    for (int j = 0; j < 4; j++)
        tile[ty + j*8][tx] = qkv[(size_t)(b*2048 + s0 + ty + j*8) * NQKV + 2560 + c0 + tx];
    __syncthreads();
    #pragma unroll
    for (int j = 0; j < 4; j++)
        vT[(size_t)(b*512 + c0 + ty + j*8) * 2048 + s0 + tx] = tile[tx][ty + j*8];
}

// ---------- MFMA flash attention: split-K + 2 waves x 32q ------------------
// Block = 128 threads (2 waves), each wave owns 32 q-rows (2 Q B-frags), so
// every K/V fragment read feeds 2 MFMAs (LDS reads per block-tile halved).
// Split-K: qt>=16 handled by two blocks (chunks of <=16 k-tiles). Chunk 1
// (owns diagonal) writes its normalized partial to ao; chunk 0 writes its
// partial to ws; both store (m,l); merge_kernel combines rows q>=1024.
// Single-buffered K/V, two-barrier async DMA schedule as r6.
__global__ __launch_bounds__(128)
void attn_mfma(const unsigned short* __restrict__ qkv,
               const unsigned short* __restrict__ vT,
               unsigned short* __restrict__ ao,
               unsigned short* __restrict__ wsP,   // 512 pairs * 64q * 128d bf16
               float2* __restrict__ wsML) {        // [pair*2+c][64q]
    __shared__ unsigned short Ks[64 * 128];   // 16KB, XOR-swizzled
    __shared__ unsigned short Vt[128 * 64];   // 16KB, XOR-swizzled

    int tid  = threadIdx.x;
    int lane = tid & 63, w = tid >> 6;        // w in {0,1}
    int quad = lane >> 4, l15 = lane & 15;
    int bx = blockIdx.x, h = blockIdx.y, b = blockIdx.z;
    int hk = h >> 2;

    // heavy-first mapping: bx<32 -> split chunks of qt 31..16; else qt 15..0
    int qt, c;
    bool split = (bx < 32);
    if (split) { qt = 31 - (bx >> 1); c = bx & 1; }
    else       { qt = 47 - bx;        c = 0;      }
    int nt = qt + 1;
    int kt_begin = 0, kt_end = nt;
    if (split) {
        int nt0 = (nt + 1) >> 1;
        kt_begin = c ? nt0 : 0;
        kt_end   = c ? nt  : nt0;
    }
    int q0 = qt * 64;
    const float scale = 0.08838834764831845f;   // 1/sqrt(128)

    // Q B-frags: qf selects 16 rows; lane l15 = q-row, k = k4*32 + quad*8
    bf16x8 aq[2][4];
    #pragma unroll
    for (int qf = 0; qf < 2; qf++) {
        const unsigned short* qrow =
            qkv + (size_t)(b*2048 + q0 + w*32 + qf*16 + l15) * NQKV + h*128;
        #pragma unroll
        for (int k4 = 0; k4 < 4; k4++)
            aq[qf][k4] = *(const bf16x8*)(qrow + k4*32 + quad*8);
    }

    // K frag offsets (s-permuted row, XOR-swizzled chunk), loop-invariant
    int koff[4][4];
    #pragma unroll
    for (int j = 0; j < 4; j++) {
        int row = ((j >> 1) * 32) + ((l15 >> 2) * 8) + ((j & 1) * 4) + (l15 & 3);
        #pragma unroll
        for (int k4 = 0; k4 < 4; k4++) {
            int slot = (k4 * 4 + quad) ^ (row & 15);
            koff[j][k4] = (row * 16 + slot) * 8;
        }
    }
    // V frag offsets fold to 2 scalars + jn*1024 immediate (row&7 == l15&7)
    int vbase0 = (l15 * 8 + (quad ^ (l15 & 7))) * 8;
    int vbase1 = (l15 * 8 + ((4 + quad) ^ (l15 & 7))) * 8;

    const unsigned short* kb0 = qkv + (size_t)(b*2048) * NQKV + 2048 + hk*128;
    const unsigned short* vb0 = vT + (size_t)(b*512 + hk*128) * 2048;

    auto stage_k = [&](int kt) {
        #pragma unroll
        for (int it = 0; it < 8; it++) {
            int s = w * 512 + it * 64 + lane;
            int r = s >> 4, qp = s & 15;
            int q = qp ^ (r & 15);
            __builtin_amdgcn_global_load_lds(
                (gas_p)(kb0 + (size_t)(kt*64 + r) * NQKV + q * 8),
                (las_p)((char*)&Ks[0] + (w * 512 + it * 64) * 16),
                16, 0, 0);
        }
    };
    auto stage_v = [&](int kt) {
        #pragma unroll
        for (int it = 0; it < 8; it++) {
            int s = w * 512 + it * 64 + lane;
            int r = s >> 3, qp = s & 7;
            int q = qp ^ (r & 7);
            __builtin_amdgcn_global_load_lds(
                (gas_p)(vb0 + (size_t)r * 2048 + kt*64 + q * 8),
                (las_p)((char*)&Vt[0] + (w * 512 + it * 64) * 16),
                16, 0, 0);
        }
    };

    f32x4 o_acc[2][8];               // O^T per qf: lane = q, rows d = quad*4+r
    const f32x4 zf = {0.f, 0.f, 0.f, 0.f};
    #pragma unroll
    for (int qf = 0; qf < 2; qf++)
        #pragma unroll
        for (int jn = 0; jn < 8; jn++) o_acc[qf][jn] = zf;
    float m_i[2] = {-1e30f, -1e30f}, l_i[2] = {0.f, 0.f};
    int qglob[2] = {q0 + w*32 + l15, q0 + w*32 + 16 + l15};

    stage_k(kt_begin);
    for (int kt = kt_begin; kt < kt_end; kt++) {
        __syncthreads();             // A: K(kt) landed; V buffer free
        stage_v(kt);                 // async during QK+softmax

        // ---- S^T = K·Q^T : shared K frag feeds both qf ----
        f32x4 s_acc[2][4];
        #pragma unroll
        for (int j = 0; j < 4; j++) {
            s_acc[0][j] = zf; s_acc[1][j] = zf;
            #pragma unroll
            for (int k4 = 0; k4 < 4; k4++) {
                bf16x8 ak = *(const bf16x8*)&Ks[koff[j][k4]];
                s_acc[0][j] = __builtin_amdgcn_mfma_f32_16x16x32_bf16(ak, aq[0][k4], s_acc[0][j], 0, 0, 0);
                s_acc[1][j] = __builtin_amdgcn_mfma_f32_16x16x32_bf16(ak, aq[1][k4], s_acc[1][j], 0, 0, 0);
            }
        }

        bf16x8 pp[2][2];
        #pragma unroll
        for (int qf = 0; qf < 2; qf++) {
            float sv[4][4];
            #pragma unroll
            for (int j = 0; j < 4; j++)
                #pragma unroll
                for (int r = 0; r < 4; r++)
                    sv[j][r] = s_acc[qf][j][r] * scale;
            if (kt == qt) {
                #pragma unroll
                for (int j = 0; j < 4; j++)
                    #pragma unroll
                    for (int r = 0; r < 4; r++) {
                        int sloc = ((j >> 1) * 32) + quad*8 + ((j & 1) * 4) + r;
                        if (kt*64 + sloc > qglob[qf]) sv[j][r] = -1e30f;
                    }
            }
            float mx = sv[0][0];
            #pragma unroll
            for (int j = 0; j < 4; j++)
                #pragma unroll
                for (int r = 0; r < 4; r++) mx = fmaxf(mx, sv[j][r]);
            mx = fmaxf(mx, __shfl_xor(mx, 16));
            mx = fmaxf(mx, __shfl_xor(mx, 32));
            float mnew = fmaxf(m_i[qf], mx);
            float alpha = __expf(m_i[qf] - mnew);
            float rs = 0.f;
            float p[4][4];
            #pragma unroll
            for (int j = 0; j < 4; j++)
                #pragma unroll
                for (int r = 0; r < 4; r++) {
                    p[j][r] = __expf(sv[j][r] - mnew);
                    rs += p[j][r];
                }
            l_i[qf] = l_i[qf] * alpha + rs;   // per-lane partial over quads
            m_i[qf] = mnew;
            #pragma unroll
            for (int jn = 0; jn < 8; jn++)
                #pragma unroll
                for (int r = 0; r < 4; r++) o_acc[qf][jn][r] *= alpha;
            #pragma unroll
            for (int r = 0; r < 4; r++) {
                pp[qf][0][r]     = (short)f2b(p[0][r]);
                pp[qf][0][r + 4] = (short)f2b(p[1][r]);
                pp[qf][1][r]     = (short)f2b(p[2][r]);
                pp[qf][1][r + 4] = (short)f2b(p[3][r]);
            }
        }

        __syncthreads();             // B: V(kt) landed; K buffer free
        if (kt + 1 < kt_end) stage_k(kt + 1);   // async during PV

        // ---- PV: shared V frag feeds both qf ----
        #pragma unroll
        for (int jn = 0; jn < 8; jn++) {
            bf16x8 av0 = *(const bf16x8*)&Vt[jn*1024 + vbase0];
            bf16x8 av1 = *(const bf16x8*)&Vt[jn*1024 + vbase1];
            o_acc[0][jn] = __builtin_amdgcn_mfma_f32_16x16x32_bf16(av0, pp[0][0], o_acc[0][jn], 0, 0, 0);
            o_acc[0][jn] = __builtin_amdgcn_mfma_f32_16x16x32_bf16(av1, pp[0][1], o_acc[0][jn], 0, 0, 0);
            o_acc[1][jn] = __builtin_amdgcn_mfma_f32_16x16x32_bf16(av0, pp[1][0], o_acc[1][jn], 0, 0, 0);
            o_acc[1][jn] = __builtin_amdgcn_mfma_f32_16x16x32_bf16(av1, pp[1][1], o_acc[1][jn], 0, 0, 0);
        }
    }

    // ---- epilogue ----
    int pidx = ((qt - 16) * 16 + h) * 2 + b;   // valid only when split
    #pragma unroll
    for (int qf = 0; qf < 2; qf++) {
        float lt = l_i[qf];
        lt += __shfl_xor(lt, 16);
        lt += __shfl_xor(lt, 32);
        float inv = 1.f / lt;
        int q_local = w*32 + qf*16 + l15;
        unsigned short* dst;
        if (!split || c == 1)
            dst = ao + (size_t)(b*2048 + q0 + q_local) * 2048 + h*128;
        else
            dst = wsP + (size_t)pidx * 8192 + q_local * 128;
        #pragma unroll
        for (int jn = 0; jn < 8; jn++) {
            ushort4 ov;
            ov.x = f2b(o_acc[qf][jn][0] * inv);
            ov.y = f2b(o_acc[qf][jn][1] * inv);
            ov.z = f2b(o_acc[qf][jn][2] * inv);
            ov.w = f2b(o_acc[qf][jn][3] * inv);
            *(ushort4*)(dst + jn*16 + quad*4) = ov;
        }
        if (split && quad == 0)
            wsML[(pidx*2 + c) * 64 + q_local] = make_float2(m_i[qf], lt);
    }
}

// ---------- merge split-K partials for rows q >= 1024 ----------------------
__global__ __launch_bounds__(256)
void merge_kernel(unsigned short* __restrict__ ao,
                  const unsigned short* __restrict__ wsP,
                  const float2* __restrict__ wsML) {
    int t = blockIdx.x * 256 + threadIdx.x;     // 2^19 threads, 8 d each
    int d  = (t & 15) * 8;
    int h  = (t >> 4) & 15;
    int qg = 1024 + ((t >> 8) & 1023);
    int b  = t >> 18;
    int qt = qg >> 6, q_local = qg & 63;
    int pidx = ((qt - 16) * 16 + h) * 2 + b;

    float2 ml0 = wsML[(pidx*2 + 0) * 64 + q_local];
    float2 ml1 = wsML[(pidx*2 + 1) * 64 + q_local];
    float mm = fmaxf(ml0.x, ml1.x);
    float f0 = __expf(ml0.x - mm) * ml0.y;
    float f1 = __expf(ml1.x - mm) * ml1.y;
    float inv = 1.f / (f0 + f1);
    f0 *= inv; f1 *= inv;

    unsigned short* arow = ao + (size_t)(b*2048 + qg) * 2048 + h*128 + d;
    const unsigned short* prow = wsP + (size_t)pidx * 8192 + q_local * 128 + d;
    ushort4 a0 = *(ushort4*)arow,        a1 = *(ushort4*)(arow + 4);
    ushort4 p0 = *(const ushort4*)prow,  p1 = *(const ushort4*)(prow + 4);
    ushort4 o0, o1;
    o0.x = f2b(f1*b2f(a0.x) + f0*b2f(p0.x));
    o0.y = f2b(f1*b2f(a0.y) + f0*b2f(p0.y));
    o0.z = f2b(f1*b2f(a0.z) + f0*b2f(p0.z));
    o0.w = f2b(f1*b2f(a0.w) + f0*b2f(p0.w));
    o1.x = f2b(f1*b2f(a1.x) + f0*b2f(p1.x));
    o1.y = f2b(f1*b2f(a1.y) + f0*b2f(p1.y));
    o1.z = f2b(f1*b2f(a1.z) + f0*b2f(p1.z));
    o1.w = f2b(f1*b2f(a1.w) + f0*b2f(p1.w));
    *(ushort4*)arow = o0;
    *(ushort4*)(arow + 4) = o1;
}

// ---------- launch ---------------------------------------------------------
extern "C" void kernel_launch(void* const* d_in, const int* in_sizes, int n_in,
                              void* d_out, int out_size, void* d_ws, size_t ws_size,
                              hipStream_t stream) {
    const float* x     = (const float*)d_in[0];
    const float* freqs = (const float*)d_in[1];
    const float* wq    = (const float*)d_in[2];
    const float* wk    = (const float*)d_in[3];
    const float* wv    = (const float*)d_in[4];
    const float* wo    = (const float*)d_in[5];
    float* out = (float*)d_out;

    char* ws = (char*)d_ws;
    unsigned short* xbf    = (unsigned short*)(ws);                  // 16MB
    unsigned short* aobuf  = (unsigned short*)(ws);                  // alias (xbf dead)
    unsigned short* wqkvT  = (unsigned short*)(ws + (16u<<20));      // 12MB
    unsigned short* woT    = (unsigned short*)(ws + (28u<<20));      // 8MB
    unsigned short* qkvbuf = (unsigned short*)(ws + (36u<<20));      // 24MB
    unsigned short* vTbuf  = (unsigned short*)(ws + (60u<<20));      // 4MB
    // split-K partials alias wqkvT (dead after gemm1):
    unsigned short* wsP    = (unsigned short*)(ws + (16u<<20));      // 8MB
    float2*         wsML   = (float2*)(ws + (24u<<20));              // 512KB

    dim3 blk(256);
    convert_x<<<8192, blk, 0, stream>>>(x, xbf);
    convert_w_t<<<dim3(64, 64), blk, 0, stream>>>(wq, 2048, wqkvT, 0);
    convert_w_t<<<dim3(16, 64), blk, 0, stream>>>(wk,  512, wqkvT, 2048);
    convert_w_t<<<dim3(16, 64), blk, 0, stream>>>(wv,  512, wqkvT, 2560);
    convert_w_t<<<dim3(64, 64), blk, 0, stream>>>(wo, 2048, woT, 0);

    gemm_bt<true><<<dim3(NQKV/128, M_/128), blk, 0, stream>>>(xbf, wqkvT, qkvbuf, NQKV);
    rope_kernel<<<20480, blk, 0, stream>>>(qkvbuf, freqs);
    v_transpose<<<dim3(64, 16, 2), blk, 0, stream>>>(qkvbuf, vTbuf);
    attn_mfma<<<dim3(48, 16, 2), dim3(128), 0, stream>>>(qkvbuf, vTbuf, aobuf, wsP, wsML);
    merge_kernel<<<2048, blk, 0, stream>>>(aobuf, wsP, wsML);
    gemm_bt<false><<<dim3(2048/128, M_/128), blk, 0, stream>>>(aobuf, woT, out, 2048);
}

// Round 8
// 345.138 us; speedup vs baseline: 1.5933x; 1.0251x over previous
//
#include <hip/hip_runtime.h>
#include <hip/hip_bf16.h>

#define B_   2
#define S_   2048
#define HID_ 2048
#define H_   16
#define KVH_ 4
#define D_   128
#define M_   4096
#define NQKV 3072

typedef __attribute__((ext_vector_type(8))) short bf16x8;   // 8 bf16 = 4 VGPR
typedef __attribute__((ext_vector_type(4))) float f32x4;
typedef const __attribute__((address_space(1))) unsigned int* gas_p;
typedef __attribute__((address_space(3))) unsigned int* las_p;

__device__ __forceinline__ unsigned short f2b(float f) {
    __hip_bfloat16 h = __float2bfloat16(f);
    return *reinterpret_cast<unsigned short*>(&h);
}
__device__ __forceinline__ float b2f(unsigned short u) {
    __hip_bfloat16 h;
    *reinterpret_cast<unsigned short*>(&h) = u;
    return __bfloat162float(h);
}

// ---------- convert x: fp32 -> bf16 ----------------------------------------
__global__ __launch_bounds__(256)
void convert_x(const float* __restrict__ x, unsigned short* __restrict__ xb) {
    int i = (blockIdx.x * 256 + threadIdx.x) * 4;
    float4 v = *(const float4*)(x + i);
    ushort4 o;
    o.x = f2b(v.x); o.y = f2b(v.y); o.z = f2b(v.z); o.w = f2b(v.w);
    *(ushort4*)(xb + i) = o;
}

// ---------- all four weight converts in one launch (z selects matrix) ------
__global__ __launch_bounds__(256)
void convert_w_all(const float* __restrict__ wq, const float* __restrict__ wk,
                   const float* __restrict__ wv, const float* __restrict__ wo,
                   unsigned short* __restrict__ wqkvT,
                   unsigned short* __restrict__ woT) {
    __shared__ float tile[32][33];
    int z = blockIdx.z;
    const float* w; int N, nbase; unsigned short* dst;
    if (z == 0)      { w = wq; N = 2048; nbase = 0;    dst = wqkvT; }
    else if (z == 1) { w = wk; N = 512;  nbase = 2048; dst = wqkvT; }
    else if (z == 2) { w = wv; N = 512;  nbase = 2560; dst = wqkvT; }
    else             { w = wo; N = 2048; nbase = 0;    dst = woT; }
    int n0 = blockIdx.x * 32, k0 = blockIdx.y * 32;
    if (n0 >= N) return;
    int tx = threadIdx.x & 31, ty = threadIdx.x >> 5;
    #pragma unroll
    for (int j = 0; j < 4; j++)
        tile[ty + j*8][tx] = w[(size_t)(k0 + ty + j*8) * N + n0 + tx];
    __syncthreads();
    #pragma unroll
    for (int j = 0; j < 4; j++)
        dst[(size_t)(nbase + n0 + ty + j*8) * 2048 + k0 + tx] = f2b(tile[tx][ty + j*8]);
}

// ---------- QKV GEMM with fused RoPE epilogue + direct V-transpose ---------
// m97 structure; col blocks are region-pure (Q<2048, K<2560, V>=2560).
// RoPE: adjacent cols = adjacent lanes in C-layout -> partner via shfl_xor(1).
// V region writes vT[(b*512+cv)][s] directly (8B/lane scatter), not qkv.
__global__ __launch_bounds__(256)
void gemm_qkv(const unsigned short* __restrict__ A,
              const unsigned short* __restrict__ BT,
              unsigned short* __restrict__ qkv,
              unsigned short* __restrict__ vT,
              const float* __restrict__ freqs) {
    __shared__ unsigned short As[128][32];
    __shared__ unsigned short Bs[128][32];

    int tid  = threadIdx.x;
    int lane = tid & 63, w = tid >> 6;
    int quad = lane >> 4, l15 = lane & 15;
    int row0 = blockIdx.y * 128, col0 = blockIdx.x * 128;
    int wm = (w & 1) * 64, wn = (w >> 1) * 64;

    f32x4 acc[4][4];
    const f32x4 zf = {0.f, 0.f, 0.f, 0.f};
    #pragma unroll
    for (int i = 0; i < 4; i++)
        #pragma unroll
        for (int j = 0; j < 4; j++) acc[i][j] = zf;

    const unsigned short* Arow = A  + (size_t)row0 * 2048;
    const unsigned short* Brow = BT + (size_t)col0 * 2048;

    for (int k0 = 0; k0 < 2048; k0 += 32) {
        #pragma unroll
        for (int it = 0; it < 2; it++) {
            int c = w * 128 + it * 64 + lane;
            int r = c >> 2, q8 = (c & 3) * 8;
            __builtin_amdgcn_global_load_lds(
                (gas_p)(Arow + (size_t)r * 2048 + k0 + q8),
                (las_p)((char*)&As[0][0] + (size_t)(w * 128 + it * 64) * 16),
                16, 0, 0);
            __builtin_amdgcn_global_load_lds(
                (gas_p)(Brow + (size_t)r * 2048 + k0 + q8),
                (las_p)((char*)&Bs[0][0] + (size_t)(w * 128 + it * 64) * 16),
                16, 0, 0);
        }
        __syncthreads();
        bf16x8 af[4], bf[4];
        #pragma unroll
        for (int i = 0; i < 4; i++) af[i] = *(const bf16x8*)&As[wm + i*16 + l15][quad * 8];
        #pragma unroll
        for (int j = 0; j < 4; j++) bf[j] = *(const bf16x8*)&Bs[wn + j*16 + l15][quad * 8];
        #pragma unroll
        for (int i = 0; i < 4; i++)
            #pragma unroll
            for (int j = 0; j < 4; j++)
                acc[i][j] = __builtin_amdgcn_mfma_f32_16x16x32_bf16(af[i], bf[j], acc[i][j], 0, 0, 0);
        __syncthreads();
    }

    bool isV = (col0 >= 2560);
    #pragma unroll
    for (int i = 0; i < 4; i++) {
        int m0 = row0 + wm + i*16 + quad*4;
        int s0 = m0 & 2047;
        if (!isV) {
            #pragma unroll
            for (int j = 0; j < 4; j++) {
                int col = col0 + wn + j*16 + l15;
                int dd = (col & 127) & ~1;
                bool odd = col & 1;
                #pragma unroll
                for (int r = 0; r < 4; r++) {
                    int s = s0 + r;
                    float cs = freqs[s*128 + dd];
                    float sn = freqs[s*128 + dd + 1];
                    float v  = acc[i][j][r];
                    float pv = __shfl_xor(v, 1);
                    float o  = odd ? (pv*sn + v*cs) : (v*cs - pv*sn);
                    qkv[(size_t)(m0 + r) * NQKV + col] = f2b(o);
                }
            }
        } else {
            #pragma unroll
            for (int j = 0; j < 4; j++) {
                int col = col0 + wn + j*16 + l15;
                int vrow = (m0 >> 11) * 512 + (col - 2560);
                ushort4 ov;
                ov.x = f2b(acc[i][j][0]);
                ov.y = f2b(acc[i][j][1]);
                ov.z = f2b(acc[i][j][2]);
                ov.w = f2b(acc[i][j][3]);
                *(ushort4*)(vT + (size_t)vrow * 2048 + s0) = ov;
            }
        }
    }
}

// ---------- plain MFMA GEMM for output projection --------------------------
__global__ __launch_bounds__(256)
void gemm_out(const unsigned short* __restrict__ A,
              const unsigned short* __restrict__ BT,
              float* __restrict__ C, int N) {
    __shared__ unsigned short As[128][32];
    __shared__ unsigned short Bs[128][32];

    int tid  = threadIdx.x;
    int lane = tid & 63, w = tid >> 6;
    int quad = lane >> 4, l15 = lane & 15;
    int row0 = blockIdx.y * 128, col0 = blockIdx.x * 128;
    int wm = (w & 1) * 64, wn = (w >> 1) * 64;

    f32x4 acc[4][4];
    const f32x4 zf = {0.f, 0.f, 0.f, 0.f};
    #pragma unroll
    for (int i = 0; i < 4; i++)
        #pragma unroll
        for (int j = 0; j < 4; j++) acc[i][j] = zf;

    const unsigned short* Arow = A  + (size_t)row0 * 2048;
    const unsigned short* Brow = BT + (size_t)col0 * 2048;

    for (int k0 = 0; k0 < 2048; k0 += 32) {
        #pragma unroll
        for (int it = 0; it < 2; it++) {
            int c = w * 128 + it * 64 + lane;
            int r = c >> 2, q8 = (c & 3) * 8;
            __builtin_amdgcn_global_load_lds(
                (gas_p)(Arow + (size_t)r * 2048 + k0 + q8),
                (las_p)((char*)&As[0][0] + (size_t)(w * 128 + it * 64) * 16),
                16, 0, 0);
            __builtin_amdgcn_global_load_lds(
                (gas_p)(Brow + (size_t)r * 2048 + k0 + q8),
                (las_p)((char*)&Bs[0][0] + (size_t)(w * 128 + it * 64) * 16),
                16, 0, 0);
        }
        __syncthreads();
        bf16x8 af[4], bf[4];
        #pragma unroll
        for (int i = 0; i < 4; i++) af[i] = *(const bf16x8*)&As[wm + i*16 + l15][quad * 8];
        #pragma unroll
        for (int j = 0; j < 4; j++) bf[j] = *(const bf16x8*)&Bs[wn + j*16 + l15][quad * 8];
        #pragma unroll
        for (int i = 0; i < 4; i++)
            #pragma unroll
            for (int j = 0; j < 4; j++)
                acc[i][j] = __builtin_amdgcn_mfma_f32_16x16x32_bf16(af[i], bf[j], acc[i][j], 0, 0, 0);
        __syncthreads();
    }

    #pragma unroll
    for (int i = 0; i < 4; i++)
        #pragma unroll
        for (int j = 0; j < 4; j++)
            #pragma unroll
            for (int r = 0; r < 4; r++)
                C[(size_t)(row0 + wm + i*16 + quad*4 + r) * N + col0 + wn + j*16 + l15]
                    = acc[i][j][r];
}

// ---------- GQA-fused MFMA flash attention ---------------------------------
// Block = (k-chunk<=14 tiles, hk, b), 512 threads / 8 waves. Wave w handles
// head hk*4+(w>>1), q-rows [(w&1)*32, +32) of the 64-row q-tile: one K/V
// staging serves 4 heads x 64 q (4x less DMA + 4x fewer tile-iterations than
// r7). Per-wave math identical to r7 (S^T form, per-lane softmax stats,
// in-register P, two-barrier single-buffer async DMA).
// Split-K: qt>=14 has 2 chunks, qt>=28 has 3. Non-last chunks write
// normalized partials + (m,l) to ws; last chunk writes ao (+ m,l if merged).
__global__ __launch_bounds__(512)
void attn_mfma(const unsigned short* __restrict__ qkv,
               const unsigned short* __restrict__ vT,
               unsigned short* __restrict__ ao,
               unsigned short* __restrict__ wsP,
               float2* __restrict__ wsML) {
    __shared__ unsigned short Ks[64 * 128];   // 16KB, XOR-swizzled
    __shared__ unsigned short Vt[128 * 64];   // 16KB, XOR-swizzled

    int tid  = threadIdx.x;
    int lane = tid & 63, w = tid >> 6;        // w in 0..7
    int quad = lane >> 4, l15 = lane & 15;
    int hw = w >> 1, qhalf = w & 1;
    int bx = blockIdx.x, hk = blockIdx.y, b = blockIdx.z;
    int h = hk * 4 + hw;

    // heavy-first (qt desc) chunk mapping: 54 (qt,c) pairs
    int qt, c;
    if (bx < 12)      { qt = 31 - bx / 3;        c = bx % 3; }
    else if (bx < 40) { qt = 27 - (bx - 12) / 2; c = (bx - 12) & 1; }
    else              { qt = 53 - bx;            c = 0; }
    int nt = qt + 1;
    int nch = (qt >= 28) ? 3 : (qt >= 14 ? 2 : 1);
    int kt_begin = c * 14;
    int kt_end = (nt < (c + 1) * 14) ? nt : (c + 1) * 14;
    bool lastc = (c == nch - 1);
    int q0 = qt * 64;
    const float scale = 0.08838834764831845f;   // 1/sqrt(128)

    // Q B-frags: lane l15 = q-row within the wave's 16; k = k4*32 + quad*8
    bf16x8 aq[2][4];
    #pragma unroll
    for (int qf = 0; qf < 2; qf++) {
        const unsigned short* qrow =
            qkv + (size_t)(b*2048 + q0 + qhalf*32 + qf*16 + l15) * NQKV + h*128;
        #pragma unroll
        for (int k4 = 0; k4 < 4; k4++)
            aq[qf][k4] = *(const bf16x8*)(qrow + k4*32 + quad*8);
    }

    // K frag offsets (s-permuted row, XOR-swizzled chunk), loop-invariant
    int koff[4][4];
    #pragma unroll
    for (int j = 0; j < 4; j++) {
        int row = ((j >> 1) * 32) + ((l15 >> 2) * 8) + ((j & 1) * 4) + (l15 & 3);
        #pragma unroll
        for (int k4 = 0; k4 < 4; k4++) {
            int slot = (k4 * 4 + quad) ^ (row & 15);
            koff[j][k4] = (row * 16 + slot) * 8;
        }
    }
    // V frag offsets fold to 2 scalars + jn*1024 immediate
    int vbase0 = (l15 * 8 + (quad ^ (l15 & 7))) * 8;
    int vbase1 = (l15 * 8 + ((4 + quad) ^ (l15 & 7))) * 8;

    const unsigned short* kb0 = qkv + (size_t)(b*2048) * NQKV + 2048 + hk*128;
    const unsigned short* vb0 = vT + (size_t)(b*512 + hk*128) * 2048;

    auto stage_k = [&](int kt) {
        #pragma unroll
        for (int it = 0; it < 2; it++) {
            int s = w * 128 + it * 64 + lane;       // 1024 chunks over 8 waves
            int r = s >> 4, qp = s & 15;
            int q = qp ^ (r & 15);
            __builtin_amdgcn_global_load_lds(
                (gas_p)(kb0 + (size_t)(kt*64 + r) * NQKV + q * 8),
                (las_p)((char*)&Ks[0] + (w * 128 + it * 64) * 16),
                16, 0, 0);
        }
    };
    auto stage_v = [&](int kt) {
        #pragma unroll
        for (int it = 0; it < 2; it++) {
            int s = w * 128 + it * 64 + lane;
            int r = s >> 3, qp = s & 7;
            int q = qp ^ (r & 7);
            __builtin_amdgcn_global_load_lds(
                (gas_p)(vb0 + (size_t)r * 2048 + kt*64 + q * 8),
                (las_p)((char*)&Vt[0] + (w * 128 + it * 64) * 16),
                16, 0, 0);
        }
    };

    f32x4 o_acc[2][8];
    const f32x4 zf = {0.f, 0.f, 0.f, 0.f};
    #pragma unroll
    for (int qf = 0; qf < 2; qf++)
        #pragma unroll
        for (int jn = 0; jn < 8; jn++) o_acc[qf][jn] = zf;
    float m_i[2] = {-1e30f, -1e30f}, l_i[2] = {0.f, 0.f};
    int qglob[2] = {q0 + qhalf*32 + l15, q0 + qhalf*32 + 16 + l15};

    stage_k(kt_begin);
    for (int kt = kt_begin; kt < kt_end; kt++) {
        __syncthreads();             // A: K(kt) landed; V buffer free
        stage_v(kt);                 // async during QK+softmax

        // ---- S^T = K·Q^T : shared K frag feeds both qf ----
        f32x4 s_acc[2][4];
        #pragma unroll
        for (int j = 0; j < 4; j++) {
            s_acc[0][j] = zf; s_acc[1][j] = zf;
            #pragma unroll
            for (int k4 = 0; k4 < 4; k4++) {
                bf16x8 ak = *(const bf16x8*)&Ks[koff[j][k4]];
                s_acc[0][j] = __builtin_amdgcn_mfma_f32_16x16x32_bf16(ak, aq[0][k4], s_acc[0][j], 0, 0, 0);
                s_acc[1][j] = __builtin_amdgcn_mfma_f32_16x16x32_bf16(ak, aq[1][k4], s_acc[1][j], 0, 0, 0);
            }
        }

        bf16x8 pp[2][2];
        #pragma unroll
        for (int qf = 0; qf < 2; qf++) {
            float sv[4][4];
            #pragma unroll
            for (int j = 0; j < 4; j++)
                #pragma unroll
                for (int r = 0; r < 4; r++)
                    sv[j][r] = s_acc[qf][j][r] * scale;
            if (kt == qt) {          // diagonal tile: only in last chunk
                #pragma unroll
                for (int j = 0; j < 4; j++)
                    #pragma unroll
                    for (int r = 0; r < 4; r++) {
                        int sloc = ((j >> 1) * 32) + quad*8 + ((j & 1) * 4) + r;
                        if (kt*64 + sloc > qglob[qf]) sv[j][r] = -1e30f;
                    }
            }
            float mx = sv[0][0];
            #pragma unroll
            for (int j = 0; j < 4; j++)
                #pragma unroll
                for (int r = 0; r < 4; r++) mx = fmaxf(mx, sv[j][r]);
            mx = fmaxf(mx, __shfl_xor(mx, 16));
            mx = fmaxf(mx, __shfl_xor(mx, 32));
            float mnew = fmaxf(m_i[qf], mx);
            float alpha = __expf(m_i[qf] - mnew);
            float rs = 0.f;
            float p[4][4];
            #pragma unroll
            for (int j = 0; j < 4; j++)
                #pragma unroll
                for (int r = 0; r < 4; r++) {
                    p[j][r] = __expf(sv[j][r] - mnew);
                    rs += p[j][r];
                }
            l_i[qf] = l_i[qf] * alpha + rs;   // per-lane partial over quads
            m_i[qf] = mnew;
            #pragma unroll
            for (int jn = 0; jn < 8; jn++)
                #pragma unroll
                for (int r = 0; r < 4; r++) o_acc[qf][jn][r] *= alpha;
            #pragma unroll
            for (int r = 0; r < 4; r++) {
                pp[qf][0][r]     = (short)f2b(p[0][r]);
                pp[qf][0][r + 4] = (short)f2b(p[1][r]);
                pp[qf][1][r]     = (short)f2b(p[2][r]);
                pp[qf][1][r + 4] = (short)f2b(p[3][r]);
            }
        }

        __syncthreads();             // B: V(kt) landed; K buffer free
        if (kt + 1 < kt_end) stage_k(kt + 1);   // async during PV

        #pragma unroll
        for (int jn = 0; jn < 8; jn++) {
            bf16x8 av0 = *(const bf16x8*)&Vt[jn*1024 + vbase0];
            bf16x8 av1 = *(const bf16x8*)&Vt[jn*1024 + vbase1];
            o_acc[0][jn] = __builtin_amdgcn_mfma_f32_16x16x32_bf16(av0, pp[0][0], o_acc[0][jn], 0, 0, 0);
            o_acc[0][jn] = __builtin_amdgcn_mfma_f32_16x16x32_bf16(av1, pp[0][1], o_acc[0][jn], 0, 0, 0);
            o_acc[1][jn] = __builtin_amdgcn_mfma_f32_16x16x32_bf16(av0, pp[1][0], o_acc[1][jn], 0, 0, 0);
            o_acc[1][jn] = __builtin_amdgcn_mfma_f32_16x16x32_bf16(av1, pp[1][1], o_acc[1][jn], 0, 0, 0);
        }
    }

    // ---- epilogue ----
    int pi = 0, mi = 0;
    if (qt >= 14) {
        if (qt < 28) { mi = (qt - 14) * 2 + c;       pi = qt - 14; }
        else         { mi = 28 + (qt - 28) * 3 + c;  pi = 14 + (qt - 28) * 2 + c; }
    }
    #pragma unroll
    for (int qf = 0; qf < 2; qf++) {
        float lt = l_i[qf];
        lt += __shfl_xor(lt, 16);
        lt += __shfl_xor(lt, 32);
        float inv = 1.f / lt;
        int q_local = qhalf * 32 + qf * 16 + l15;
        unsigned short* dst;
        if (lastc)
            dst = ao + (size_t)(b*2048 + q0 + q_local) * 2048 + h*128;
        else
            dst = wsP + (size_t)(((pi * 8 + hk * 2 + b) * 4 + hw) * 64 + q_local) * 128;
        #pragma unroll
        for (int jn = 0; jn < 8; jn++) {
            ushort4 ov;
            ov.x = f2b(o_acc[qf][jn][0] * inv);
            ov.y = f2b(o_acc[qf][jn][1] * inv);
            ov.z = f2b(o_acc[qf][jn][2] * inv);
            ov.w = f2b(o_acc[qf][jn][3] * inv);
            *(ushort4*)(dst + jn*16 + quad*4) = ov;
        }
        if (qt >= 14 && quad == 0)
            wsML[(mi * 8 + hk * 2 + b) * 256 + hw * 64 + q_local]
                = make_float2(m_i[qf], lt);
    }
}

// ---------- merge split-K partials (rows q >= 896, 2-3 chunks) -------------
__global__ __launch_bounds__(256)
void merge_kernel(unsigned short* __restrict__ ao,
                  const unsigned short* __restrict__ wsP,
                  const float2* __restrict__ wsML) {
    int t = blockIdx.x * 256 + threadIdx.x;
    int d = (t & 15) * 8;
    int h = (t >> 4) & 15;
    int rest = t >> 8;                // 0..2303
    int q_off = rest % 1152;
    int b = rest / 1152;
    int q = 896 + q_off;
    int qt = q >> 6, q_local = q & 63;
    int hk = h >> 2, hw = h & 3;
    int nch = (qt >= 28) ? 3 : 2;

    float mv[3], lv[3];
    for (int cc = 0; cc < nch; cc++) {
        int mi = (qt < 28) ? (qt - 14) * 2 + cc : 28 + (qt - 28) * 3 + cc;
        float2 ml = wsML[(mi * 8 + hk * 2 + b) * 256 + hw * 64 + q_local];
        mv[cc] = ml.x; lv[cc] = ml.y;
    }
    float M = mv[0];
    for (int cc = 1; cc < nch; cc++) M = fmaxf(M, mv[cc]);
    float f[3], S = 0.f;
    for (int cc = 0; cc < nch; cc++) { f[cc] = __expf(mv[cc] - M) * lv[cc]; S += f[cc]; }
    float inv = 1.f / S;

    unsigned short* arow = ao + (size_t)(b*2048 + q) * 2048 + h*128 + d;
    float outv[8];
    {   // last chunk lives in ao
        ushort4 a0 = *(ushort4*)arow, a1 = *(ushort4*)(arow + 4);
        float fl = f[nch-1];
        outv[0] = fl*b2f(a0.x); outv[1] = fl*b2f(a0.y);
        outv[2] = fl*b2f(a0.z); outv[3] = fl*b2f(a0.w);
        outv[4] = fl*b2f(a1.x); outv[5] = fl*b2f(a1.y);
        outv[6] = fl*b2f(a1.z); outv[7] = fl*b2f(a1.w);
    }
    for (int cc = 0; cc < nch - 1; cc++) {
        int pi = (qt < 28) ? (qt - 14) : 14 + (qt - 28) * 2 + cc;
        const unsigned short* prow =
            wsP + (size_t)(((pi * 8 + hk * 2 + b) * 4 + hw) * 64 + q_local) * 128 + d;
        ushort4 p0 = *(const ushort4*)prow, p1 = *(const ushort4*)(prow + 4);
        float fc = f[cc];
        outv[0] += fc*b2f(p0.x); outv[1] += fc*b2f(p0.y);
        outv[2] += fc*b2f(p0.z); outv[3] += fc*b2f(p0.w);
        outv[4] += fc*b2f(p1.x); outv[5] += fc*b2f(p1.y);
        outv[6] += fc*b2f(p1.z); outv[7] += fc*b2f(p1.w);
    }
    ushort4 o0, o1;
    o0.x = f2b(outv[0]*inv); o0.y = f2b(outv[1]*inv);
    o0.z = f2b(outv[2]*inv); o0.w = f2b(outv[3]*inv);
    o1.x = f2b(outv[4]*inv); o1.y = f2b(outv[5]*inv);
    o1.z = f2b(outv[6]*inv); o1.w = f2b(outv[7]*inv);
    *(ushort4*)arow = o0;
    *(ushort4*)(arow + 4) = o1;
}

// ---------- launch ---------------------------------------------------------
extern "C" void kernel_launch(void* const* d_in, const int* in_sizes, int n_in,
                              void* d_out, int out_size, void* d_ws, size_t ws_size,
                              hipStream_t stream) {
    const float* x     = (const float*)d_in[0];
    const float* freqs = (const float*)d_in[1];
    const float* wq    = (const float*)d_in[2];
    const float* wk    = (const float*)d_in[3];
    const float* wv    = (const float*)d_in[4];
    const float* wo    = (const float*)d_in[5];
    float* out = (float*)d_out;

    char* ws = (char*)d_ws;
    unsigned short* xbf    = (unsigned short*)(ws);                  // 16MB
    unsigned short* aobuf  = (unsigned short*)(ws);                  // alias (xbf dead)
    unsigned short* wqkvT  = (unsigned short*)(ws + (16u<<20));      // 12MB
    unsigned short* woT    = (unsigned short*)(ws + (28u<<20));      // 8MB
    unsigned short* qkvbuf = (unsigned short*)(ws + (36u<<20));      // 24MB
    unsigned short* vTbuf  = (unsigned short*)(ws + (60u<<20));      // 4MB
    // split-K partials alias wqkvT (dead after gemm_qkv):
    unsigned short* wsP  = (unsigned short*)(ws + (16u<<20));        // 11MB
    float2*         wsML = (float2*)(ws + (16u<<20) + 176u*65536u);  // 640KB

    dim3 blk(256);
    convert_x<<<8192, blk, 0, stream>>>(x, xbf);
    convert_w_all<<<dim3(64, 64, 4), blk, 0, stream>>>(wq, wk, wv, wo, wqkvT, woT);
    gemm_qkv<<<dim3(NQKV/128, M_/128), blk, 0, stream>>>(xbf, wqkvT, qkvbuf, vTbuf, freqs);
    attn_mfma<<<dim3(54, 4, 2), dim3(512), 0, stream>>>(qkvbuf, vTbuf, aobuf, wsP, wsML);
    merge_kernel<<<2304, blk, 0, stream>>>(aobuf, wsP, wsML);
    gemm_out<<<dim3(2048/128, M_/128), blk, 0, stream>>>(aobuf, woT, out, 2048);
}

// Round 9
// 328.479 us; speedup vs baseline: 1.6741x; 1.0507x over previous
//
#include <hip/hip_runtime.h>
#include <hip/hip_bf16.h>

#define B_   2
#define S_   2048
#define HID_ 2048
#define H_   16
#define KVH_ 4
#define D_   128
#define M_   4096
#define NQKV 3072

typedef __attribute__((ext_vector_type(8))) short bf16x8;   // 8 bf16 = 4 VGPR
typedef __attribute__((ext_vector_type(4))) float f32x4;
typedef const __attribute__((address_space(1))) unsigned int* gas_p;
typedef __attribute__((address_space(3))) unsigned int* las_p;

__device__ __forceinline__ unsigned short f2b(float f) {
    __hip_bfloat16 h = __float2bfloat16(f);
    return *reinterpret_cast<unsigned short*>(&h);
}
__device__ __forceinline__ float b2f(unsigned short u) {
    __hip_bfloat16 h;
    *reinterpret_cast<unsigned short*>(&h) = u;
    return __bfloat162float(h);
}

// ---------- convert x: fp32 -> bf16 ----------------------------------------
__global__ __launch_bounds__(256)
void convert_x(const float* __restrict__ x, unsigned short* __restrict__ xb) {
    int i = (blockIdx.x * 256 + threadIdx.x) * 4;
    float4 v = *(const float4*)(x + i);
    ushort4 o;
    o.x = f2b(v.x); o.y = f2b(v.y); o.z = f2b(v.z); o.w = f2b(v.w);
    *(ushort4*)(xb + i) = o;
}

// ---------- all four weight converts in one launch (z selects matrix) ------
__global__ __launch_bounds__(256)
void convert_w_all(const float* __restrict__ wq, const float* __restrict__ wk,
                   const float* __restrict__ wv, const float* __restrict__ wo,
                   unsigned short* __restrict__ wqkvT,
                   unsigned short* __restrict__ woT) {
    __shared__ float tile[32][33];
    int z = blockIdx.z;
    const float* w; int N, nbase; unsigned short* dst;
    if (z == 0)      { w = wq; N = 2048; nbase = 0;    dst = wqkvT; }
    else if (z == 1) { w = wk; N = 512;  nbase = 2048; dst = wqkvT; }
    else if (z == 2) { w = wv; N = 512;  nbase = 2560; dst = wqkvT; }
    else             { w = wo; N = 2048; nbase = 0;    dst = woT; }
    int n0 = blockIdx.x * 32, k0 = blockIdx.y * 32;
    if (n0 >= N) return;
    int tx = threadIdx.x & 31, ty = threadIdx.x >> 5;
    #pragma unroll
    for (int j = 0; j < 4; j++)
        tile[ty + j*8][tx] = w[(size_t)(k0 + ty + j*8) * N + n0 + tx];
    __syncthreads();
    #pragma unroll
    for (int j = 0; j < 4; j++)
        dst[(size_t)(nbase + n0 + ty + j*8) * 2048 + k0 + tx] = f2b(tile[tx][ty + j*8]);
}

// ---------- QKV GEMM, BK=64, XOR-swizzled LDS, fused RoPE + V-transpose ----
// 128x128 tile, BK=64 (32 k-iters, half the barrier drains of BK=32).
// LDS row = 128B = exactly 32 banks, so unswizzled frag reads would be
// 16-way conflicted; chunk q of row r lives at slot q^(r&7) -> frag b128
// reads land 8 lanes per 4-bank group, groups parallel = LDS floor.
// DMA dest stays linear (wave-uniform base + lane*16); source addr inverts
// the swizzle. RoPE epilogue identical to r8.
__global__ __launch_bounds__(256)
void gemm_qkv(const unsigned short* __restrict__ A,
              const unsigned short* __restrict__ BT,
              unsigned short* __restrict__ qkv,
              unsigned short* __restrict__ vT,
              const float* __restrict__ freqs) {
    __shared__ unsigned short As[128 * 64];
    __shared__ unsigned short Bs[128 * 64];

    int tid  = threadIdx.x;
    int lane = tid & 63, w = tid >> 6;
    int quad = lane >> 4, l15 = lane & 15;
    int row0 = blockIdx.y * 128, col0 = blockIdx.x * 128;
    int wm = (w & 1) * 64, wn = (w >> 1) * 64;

    f32x4 acc[4][4];
    const f32x4 zf = {0.f, 0.f, 0.f, 0.f};
    #pragma unroll
    for (int i = 0; i < 4; i++)
        #pragma unroll
        for (int j = 0; j < 4; j++) acc[i][j] = zf;

    const unsigned short* Arow = A  + (size_t)row0 * 2048;
    const unsigned short* Brow = BT + (size_t)col0 * 2048;

    for (int k0 = 0; k0 < 2048; k0 += 64) {
        #pragma unroll
        for (int it = 0; it < 4; it++) {
            int c = w * 256 + it * 64 + lane;          // chunk 0..1023
            int r = c >> 3, qp = c & 7;
            int q8 = (qp ^ (r & 7)) * 8;               // inverse swizzle
            __builtin_amdgcn_global_load_lds(
                (gas_p)(Arow + (size_t)r * 2048 + k0 + q8),
                (las_p)((char*)&As[0] + (size_t)(w * 256 + it * 64) * 16),
                16, 0, 0);
            __builtin_amdgcn_global_load_lds(
                (gas_p)(Brow + (size_t)r * 2048 + k0 + q8),
                (las_p)((char*)&Bs[0] + (size_t)(w * 256 + it * 64) * 16),
                16, 0, 0);
        }
        __syncthreads();
        #pragma unroll
        for (int kk = 0; kk < 2; kk++) {
            int slot = ((kk * 4 + quad) ^ (l15 & 7)) * 8;
            bf16x8 af[4], bf[4];
            #pragma unroll
            for (int i = 0; i < 4; i++)
                af[i] = *(const bf16x8*)&As[(wm + i*16 + l15) * 64 + slot];
            #pragma unroll
            for (int j = 0; j < 4; j++)
                bf[j] = *(const bf16x8*)&Bs[(wn + j*16 + l15) * 64 + slot];
            #pragma unroll
            for (int i = 0; i < 4; i++)
                #pragma unroll
                for (int j = 0; j < 4; j++)
                    acc[i][j] = __builtin_amdgcn_mfma_f32_16x16x32_bf16(af[i], bf[j], acc[i][j], 0, 0, 0);
        }
        __syncthreads();
    }

    bool isV = (col0 >= 2560);
    #pragma unroll
    for (int i = 0; i < 4; i++) {
        int m0 = row0 + wm + i*16 + quad*4;
        int s0 = m0 & 2047;
        if (!isV) {
            #pragma unroll
            for (int j = 0; j < 4; j++) {
                int col = col0 + wn + j*16 + l15;
                int dd = (col & 127) & ~1;
                bool odd = col & 1;
                #pragma unroll
                for (int r = 0; r < 4; r++) {
                    int s = s0 + r;
                    float cs = freqs[s*128 + dd];
                    float sn = freqs[s*128 + dd + 1];
                    float v  = acc[i][j][r];
                    float pv = __shfl_xor(v, 1);
                    float o  = odd ? (pv*sn + v*cs) : (v*cs - pv*sn);
                    qkv[(size_t)(m0 + r) * NQKV + col] = f2b(o);
                }
            }
        } else {
            #pragma unroll
            for (int j = 0; j < 4; j++) {
                int col = col0 + wn + j*16 + l15;
                int vrow = (m0 >> 11) * 512 + (col - 2560);
                ushort4 ov;
                ov.x = f2b(acc[i][j][0]);
                ov.y = f2b(acc[i][j][1]);
                ov.z = f2b(acc[i][j][2]);
                ov.w = f2b(acc[i][j][3]);
                *(ushort4*)(vT + (size_t)vrow * 2048 + s0) = ov;
            }
        }
    }
}

// ---------- output projection GEMM, BK=64, XOR-swizzled --------------------
__global__ __launch_bounds__(256)
void gemm_out(const unsigned short* __restrict__ A,
              const unsigned short* __restrict__ BT,
              float* __restrict__ C, int N) {
    __shared__ unsigned short As[128 * 64];
    __shared__ unsigned short Bs[128 * 64];

    int tid  = threadIdx.x;
    int lane = tid & 63, w = tid >> 6;
    int quad = lane >> 4, l15 = lane & 15;
    int row0 = blockIdx.y * 128, col0 = blockIdx.x * 128;
    int wm = (w & 1) * 64, wn = (w >> 1) * 64;

    f32x4 acc[4][4];
    const f32x4 zf = {0.f, 0.f, 0.f, 0.f};
    #pragma unroll
    for (int i = 0; i < 4; i++)
        #pragma unroll
        for (int j = 0; j < 4; j++) acc[i][j] = zf;

    const unsigned short* Arow = A  + (size_t)row0 * 2048;
    const unsigned short* Brow = BT + (size_t)col0 * 2048;

    for (int k0 = 0; k0 < 2048; k0 += 64) {
        #pragma unroll
        for (int it = 0; it < 4; it++) {
            int c = w * 256 + it * 64 + lane;
            int r = c >> 3, qp = c & 7;
            int q8 = (qp ^ (r & 7)) * 8;
            __builtin_amdgcn_global_load_lds(
                (gas_p)(Arow + (size_t)r * 2048 + k0 + q8),
                (las_p)((char*)&As[0] + (size_t)(w * 256 + it * 64) * 16),
                16, 0, 0);
            __builtin_amdgcn_global_load_lds(
                (gas_p)(Brow + (size_t)r * 2048 + k0 + q8),
                (las_p)((char*)&Bs[0] + (size_t)(w * 256 + it * 64) * 16),
                16, 0, 0);
        }
        __syncthreads();
        #pragma unroll
        for (int kk = 0; kk < 2; kk++) {
            int slot = ((kk * 4 + quad) ^ (l15 & 7)) * 8;
            bf16x8 af[4], bf[4];
            #pragma unroll
            for (int i = 0; i < 4; i++)
                af[i] = *(const bf16x8*)&As[(wm + i*16 + l15) * 64 + slot];
            #pragma unroll
            for (int j = 0; j < 4; j++)
                bf[j] = *(const bf16x8*)&Bs[(wn + j*16 + l15) * 64 + slot];
            #pragma unroll
            for (int i = 0; i < 4; i++)
                #pragma unroll
                for (int j = 0; j < 4; j++)
                    acc[i][j] = __builtin_amdgcn_mfma_f32_16x16x32_bf16(af[i], bf[j], acc[i][j], 0, 0, 0);
        }
        __syncthreads();
    }

    #pragma unroll
    for (int i = 0; i < 4; i++)
        #pragma unroll
        for (int j = 0; j < 4; j++)
            #pragma unroll
            for (int r = 0; r < 4; r++)
                C[(size_t)(row0 + wm + i*16 + quad*4 + r) * N + col0 + wn + j*16 + l15]
                    = acc[i][j][r];
}

// ---------- GQA-fused MFMA flash attention (unchanged from r8) -------------
__global__ __launch_bounds__(512)
void attn_mfma(const unsigned short* __restrict__ qkv,
               const unsigned short* __restrict__ vT,
               unsigned short* __restrict__ ao,
               unsigned short* __restrict__ wsP,
               float2* __restrict__ wsML) {
    __shared__ unsigned short Ks[64 * 128];   // 16KB, XOR-swizzled
    __shared__ unsigned short Vt[128 * 64];   // 16KB, XOR-swizzled

    int tid  = threadIdx.x;
    int lane = tid & 63, w = tid >> 6;        // w in 0..7
    int quad = lane >> 4, l15 = lane & 15;
    int hw = w >> 1, qhalf = w & 1;
    int bx = blockIdx.x, hk = blockIdx.y, b = blockIdx.z;
    int h = hk * 4 + hw;

    int qt, c;
    if (bx < 12)      { qt = 31 - bx / 3;        c = bx % 3; }
    else if (bx < 40) { qt = 27 - (bx - 12) / 2; c = (bx - 12) & 1; }
    else              { qt = 53 - bx;            c = 0; }
    int nt = qt + 1;
    int nch = (qt >= 28) ? 3 : (qt >= 14 ? 2 : 1);
    int kt_begin = c * 14;
    int kt_end = (nt < (c + 1) * 14) ? nt : (c + 1) * 14;
    bool lastc = (c == nch - 1);
    int q0 = qt * 64;
    const float scale = 0.08838834764831845f;   // 1/sqrt(128)

    bf16x8 aq[2][4];
    #pragma unroll
    for (int qf = 0; qf < 2; qf++) {
        const unsigned short* qrow =
            qkv + (size_t)(b*2048 + q0 + qhalf*32 + qf*16 + l15) * NQKV + h*128;
        #pragma unroll
        for (int k4 = 0; k4 < 4; k4++)
            aq[qf][k4] = *(const bf16x8*)(qrow + k4*32 + quad*8);
    }

    int koff[4][4];
    #pragma unroll
    for (int j = 0; j < 4; j++) {
        int row = ((j >> 1) * 32) + ((l15 >> 2) * 8) + ((j & 1) * 4) + (l15 & 3);
        #pragma unroll
        for (int k4 = 0; k4 < 4; k4++) {
            int slot = (k4 * 4 + quad) ^ (row & 15);
            koff[j][k4] = (row * 16 + slot) * 8;
        }
    }
    int vbase0 = (l15 * 8 + (quad ^ (l15 & 7))) * 8;
    int vbase1 = (l15 * 8 + ((4 + quad) ^ (l15 & 7))) * 8;

    const unsigned short* kb0 = qkv + (size_t)(b*2048) * NQKV + 2048 + hk*128;
    const unsigned short* vb0 = vT + (size_t)(b*512 + hk*128) * 2048;

    auto stage_k = [&](int kt) {
        #pragma unroll
        for (int it = 0; it < 2; it++) {
            int s = w * 128 + it * 64 + lane;
            int r = s >> 4, qp = s & 15;
            int q = qp ^ (r & 15);
            __builtin_amdgcn_global_load_lds(
                (gas_p)(kb0 + (size_t)(kt*64 + r) * NQKV + q * 8),
                (las_p)((char*)&Ks[0] + (w * 128 + it * 64) * 16),
                16, 0, 0);
        }
    };
    auto stage_v = [&](int kt) {
        #pragma unroll
        for (int it = 0; it < 2; it++) {
            int s = w * 128 + it * 64 + lane;
            int r = s >> 3, qp = s & 7;
            int q = qp ^ (r & 7);
            __builtin_amdgcn_global_load_lds(
                (gas_p)(vb0 + (size_t)r * 2048 + kt*64 + q * 8),
                (las_p)((char*)&Vt[0] + (w * 128 + it * 64) * 16),
                16, 0, 0);
        }
    };

    f32x4 o_acc[2][8];
    const f32x4 zf = {0.f, 0.f, 0.f, 0.f};
    #pragma unroll
    for (int qf = 0; qf < 2; qf++)
        #pragma unroll
        for (int jn = 0; jn < 8; jn++) o_acc[qf][jn] = zf;
    float m_i[2] = {-1e30f, -1e30f}, l_i[2] = {0.f, 0.f};
    int qglob[2] = {q0 + qhalf*32 + l15, q0 + qhalf*32 + 16 + l15};

    stage_k(kt_begin);
    for (int kt = kt_begin; kt < kt_end; kt++) {
        __syncthreads();             // A: K(kt) landed; V buffer free
        stage_v(kt);                 // async during QK+softmax

        f32x4 s_acc[2][4];
        #pragma unroll
        for (int j = 0; j < 4; j++) {
            s_acc[0][j] = zf; s_acc[1][j] = zf;
            #pragma unroll
            for (int k4 = 0; k4 < 4; k4++) {
                bf16x8 ak = *(const bf16x8*)&Ks[koff[j][k4]];
                s_acc[0][j] = __builtin_amdgcn_mfma_f32_16x16x32_bf16(ak, aq[0][k4], s_acc[0][j], 0, 0, 0);
                s_acc[1][j] = __builtin_amdgcn_mfma_f32_16x16x32_bf16(ak, aq[1][k4], s_acc[1][j], 0, 0, 0);
            }
        }

        bf16x8 pp[2][2];
        #pragma unroll
        for (int qf = 0; qf < 2; qf++) {
            float sv[4][4];
            #pragma unroll
            for (int j = 0; j < 4; j++)
                #pragma unroll
                for (int r = 0; r < 4; r++)
                    sv[j][r] = s_acc[qf][j][r] * scale;
            if (kt == qt) {
                #pragma unroll
                for (int j = 0; j < 4; j++)
                    #pragma unroll
                    for (int r = 0; r < 4; r++) {
                        int sloc = ((j >> 1) * 32) + quad*8 + ((j & 1) * 4) + r;
                        if (kt*64 + sloc > qglob[qf]) sv[j][r] = -1e30f;
                    }
            }
            float mx = sv[0][0];
            #pragma unroll
            for (int j = 0; j < 4; j++)
                #pragma unroll
                for (int r = 0; r < 4; r++) mx = fmaxf(mx, sv[j][r]);
            mx = fmaxf(mx, __shfl_xor(mx, 16));
            mx = fmaxf(mx, __shfl_xor(mx, 32));
            float mnew = fmaxf(m_i[qf], mx);
            float alpha = __expf(m_i[qf] - mnew);
            float rs = 0.f;
            float p[4][4];
            #pragma unroll
            for (int j = 0; j < 4; j++)
                #pragma unroll
                for (int r = 0; r < 4; r++) {
                    p[j][r] = __expf(sv[j][r] - mnew);
                    rs += p[j][r];
                }
            l_i[qf] = l_i[qf] * alpha + rs;
            m_i[qf] = mnew;
            #pragma unroll
            for (int jn = 0; jn < 8; jn++)
                #pragma unroll
                for (int r = 0; r < 4; r++) o_acc[qf][jn][r] *= alpha;
            #pragma unroll
            for (int r = 0; r < 4; r++) {
                pp[qf][0][r]     = (short)f2b(p[0][r]);
                pp[qf][0][r + 4] = (short)f2b(p[1][r]);
                pp[qf][1][r]     = (short)f2b(p[2][r]);
                pp[qf][1][r + 4] = (short)f2b(p[3][r]);
            }
        }

        __syncthreads();             // B: V(kt) landed; K buffer free
        if (kt + 1 < kt_end) stage_k(kt + 1);

        #pragma unroll
        for (int jn = 0; jn < 8; jn++) {
            bf16x8 av0 = *(const bf16x8*)&Vt[jn*1024 + vbase0];
            bf16x8 av1 = *(const bf16x8*)&Vt[jn*1024 + vbase1];
            o_acc[0][jn] = __builtin_amdgcn_mfma_f32_16x16x32_bf16(av0, pp[0][0], o_acc[0][jn], 0, 0, 0);
            o_acc[0][jn] = __builtin_amdgcn_mfma_f32_16x16x32_bf16(av1, pp[0][1], o_acc[0][jn], 0, 0, 0);
            o_acc[1][jn] = __builtin_amdgcn_mfma_f32_16x16x32_bf16(av0, pp[1][0], o_acc[1][jn], 0, 0, 0);
            o_acc[1][jn] = __builtin_amdgcn_mfma_f32_16x16x32_bf16(av1, pp[1][1], o_acc[1][jn], 0, 0, 0);
        }
    }

    int pi = 0, mi = 0;
    if (qt >= 14) {
        if (qt < 28) { mi = (qt - 14) * 2 + c;       pi = qt - 14; }
        else         { mi = 28 + (qt - 28) * 3 + c;  pi = 14 + (qt - 28) * 2 + c; }
    }
    #pragma unroll
    for (int qf = 0; qf < 2; qf++) {
        float lt = l_i[qf];
        lt += __shfl_xor(lt, 16);
        lt += __shfl_xor(lt, 32);
        float inv = 1.f / lt;
        int q_local = qhalf * 32 + qf * 16 + l15;
        unsigned short* dst;
        if (lastc)
            dst = ao + (size_t)(b*2048 + q0 + q_local) * 2048 + h*128;
        else
            dst = wsP + (size_t)(((pi * 8 + hk * 2 + b) * 4 + hw) * 64 + q_local) * 128;
        #pragma unroll
        for (int jn = 0; jn < 8; jn++) {
            ushort4 ov;
            ov.x = f2b(o_acc[qf][jn][0] * inv);
            ov.y = f2b(o_acc[qf][jn][1] * inv);
            ov.z = f2b(o_acc[qf][jn][2] * inv);
            ov.w = f2b(o_acc[qf][jn][3] * inv);
            *(ushort4*)(dst + jn*16 + quad*4) = ov;
        }
        if (qt >= 14 && quad == 0)
            wsML[(mi * 8 + hk * 2 + b) * 256 + hw * 64 + q_local]
                = make_float2(m_i[qf], lt);
    }
}

// ---------- merge split-K partials (rows q >= 896, 2-3 chunks) -------------
__global__ __launch_bounds__(256)
void merge_kernel(unsigned short* __restrict__ ao,
                  const unsigned short* __restrict__ wsP,
                  const float2* __restrict__ wsML) {
    int t = blockIdx.x * 256 + threadIdx.x;
    int d = (t & 15) * 8;
    int h = (t >> 4) & 15;
    int rest = t >> 8;                // 0..2303
    int q_off = rest % 1152;
    int b = rest / 1152;
    int q = 896 + q_off;
    int qt = q >> 6, q_local = q & 63;
    int hk = h >> 2, hw = h & 3;
    int nch = (qt >= 28) ? 3 : 2;

    float mv[3], lv[3];
    for (int cc = 0; cc < nch; cc++) {
        int mi = (qt < 28) ? (qt - 14) * 2 + cc : 28 + (qt - 28) * 3 + cc;
        float2 ml = wsML[(mi * 8 + hk * 2 + b) * 256 + hw * 64 + q_local];
        mv[cc] = ml.x; lv[cc] = ml.y;
    }
    float M = mv[0];
    for (int cc = 1; cc < nch; cc++) M = fmaxf(M, mv[cc]);
    float f[3], S = 0.f;
    for (int cc = 0; cc < nch; cc++) { f[cc] = __expf(mv[cc] - M) * lv[cc]; S += f[cc]; }
    float inv = 1.f / S;

    unsigned short* arow = ao + (size_t)(b*2048 + q) * 2048 + h*128 + d;
    float outv[8];
    {
        ushort4 a0 = *(ushort4*)arow, a1 = *(ushort4*)(arow + 4);
        float fl = f[nch-1];
        outv[0] = fl*b2f(a0.x); outv[1] = fl*b2f(a0.y);
        outv[2] = fl*b2f(a0.z); outv[3] = fl*b2f(a0.w);
        outv[4] = fl*b2f(a1.x); outv[5] = fl*b2f(a1.y);
        outv[6] = fl*b2f(a1.z); outv[7] = fl*b2f(a1.w);
    }
    for (int cc = 0; cc < nch - 1; cc++) {
        int pi = (qt < 28) ? (qt - 14) : 14 + (qt - 28) * 2 + cc;
        const unsigned short* prow =
            wsP + (size_t)(((pi * 8 + hk * 2 + b) * 4 + hw) * 64 + q_local) * 128 + d;
        ushort4 p0 = *(const ushort4*)prow, p1 = *(const ushort4*)(prow + 4);
        float fc = f[cc];
        outv[0] += fc*b2f(p0.x); outv[1] += fc*b2f(p0.y);
        outv[2] += fc*b2f(p0.z); outv[3] += fc*b2f(p0.w);
        outv[4] += fc*b2f(p1.x); outv[5] += fc*b2f(p1.y);
        outv[6] += fc*b2f(p1.z); outv[7] += fc*b2f(p1.w);
    }
    ushort4 o0, o1;
    o0.x = f2b(outv[0]*inv); o0.y = f2b(outv[1]*inv);
    o0.z = f2b(outv[2]*inv); o0.w = f2b(outv[3]*inv);
    o1.x = f2b(outv[4]*inv); o1.y = f2b(outv[5]*inv);
    o1.z = f2b(outv[6]*inv); o1.w = f2b(outv[7]*inv);
    *(ushort4*)arow = o0;
    *(ushort4*)(arow + 4) = o1;
}

// ---------- launch ---------------------------------------------------------
extern "C" void kernel_launch(void* const* d_in, const int* in_sizes, int n_in,
                              void* d_out, int out_size, void* d_ws, size_t ws_size,
                              hipStream_t stream) {
    const float* x     = (const float*)d_in[0];
    const float* freqs = (const float*)d_in[1];
    const float* wq    = (const float*)d_in[2];
    const float* wk    = (const float*)d_in[3];
    const float* wv    = (const float*)d_in[4];
    const float* wo    = (const float*)d_in[5];
    float* out = (float*)d_out;

    char* ws = (char*)d_ws;
    unsigned short* xbf    = (unsigned short*)(ws);                  // 16MB
    unsigned short* aobuf  = (unsigned short*)(ws);                  // alias (xbf dead)
    unsigned short* wqkvT  = (unsigned short*)(ws + (16u<<20));      // 12MB
    unsigned short* woT    = (unsigned short*)(ws + (28u<<20));      // 8MB
    unsigned short* qkvbuf = (unsigned short*)(ws + (36u<<20));      // 24MB
    unsigned short* vTbuf  = (unsigned short*)(ws + (60u<<20));      // 4MB
    unsigned short* wsP  = (unsigned short*)(ws + (16u<<20));        // 11MB (aliases wqkvT, dead)
    float2*         wsML = (float2*)(ws + (16u<<20) + 176u*65536u);  // 640KB

    dim3 blk(256);
    convert_x<<<8192, blk, 0, stream>>>(x, xbf);
    convert_w_all<<<dim3(64, 64, 4), blk, 0, stream>>>(wq, wk, wv, wo, wqkvT, woT);
    gemm_qkv<<<dim3(NQKV/128, M_/128), blk, 0, stream>>>(xbf, wqkvT, qkvbuf, vTbuf, freqs);
    attn_mfma<<<dim3(54, 4, 2), dim3(512), 0, stream>>>(qkvbuf, vTbuf, aobuf, wsP, wsML);
    merge_kernel<<<2304, blk, 0, stream>>>(aobuf, wsP, wsML);
    gemm_out<<<dim3(2048/128, M_/128), blk, 0, stream>>>(aobuf, woT, out, 2048);
}

// Round 10
// 322.600 us; speedup vs baseline: 1.7046x; 1.0182x over previous
//
#include <hip/hip_runtime.h>
#include <hip/hip_bf16.h>

#define B_   2
#define S_   2048
#define HID_ 2048
#define H_   16
#define KVH_ 4
#define D_   128
#define M_   4096
#define NQKV 3072

typedef __attribute__((ext_vector_type(8))) short bf16x8;    // 8 bf16 = 4 VGPR
typedef __attribute__((ext_vector_type(4))) float f32x4;
typedef __attribute__((ext_vector_type(16))) float f32x16;
typedef const __attribute__((address_space(1))) unsigned int* gas_p;
typedef __attribute__((address_space(3))) unsigned int* las_p;

__device__ __forceinline__ unsigned short f2b(float f) {
    __hip_bfloat16 h = __float2bfloat16(f);
    return *reinterpret_cast<unsigned short*>(&h);
}
__device__ __forceinline__ float b2f(unsigned short u) {
    __hip_bfloat16 h;
    *reinterpret_cast<unsigned short*>(&h) = u;
    return __bfloat162float(h);
}

// ---------- convert x: fp32 -> bf16 ----------------------------------------
__global__ __launch_bounds__(256)
void convert_x(const float* __restrict__ x, unsigned short* __restrict__ xb) {
    int i = (blockIdx.x * 256 + threadIdx.x) * 4;
    float4 v = *(const float4*)(x + i);
    ushort4 o;
    o.x = f2b(v.x); o.y = f2b(v.y); o.z = f2b(v.z); o.w = f2b(v.w);
    *(ushort4*)(xb + i) = o;
}

// ---------- all four weight converts in one launch (z selects matrix) ------
__global__ __launch_bounds__(256)
void convert_w_all(const float* __restrict__ wq, const float* __restrict__ wk,
                   const float* __restrict__ wv, const float* __restrict__ wo,
                   unsigned short* __restrict__ wqkvT,
                   unsigned short* __restrict__ woT) {
    __shared__ float tile[32][33];
    int z = blockIdx.z;
    const float* w; int N, nbase; unsigned short* dst;
    if (z == 0)      { w = wq; N = 2048; nbase = 0;    dst = wqkvT; }
    else if (z == 1) { w = wk; N = 512;  nbase = 2048; dst = wqkvT; }
    else if (z == 2) { w = wv; N = 512;  nbase = 2560; dst = wqkvT; }
    else             { w = wo; N = 2048; nbase = 0;    dst = woT; }
    int n0 = blockIdx.x * 32, k0 = blockIdx.y * 32;
    if (n0 >= N) return;
    int tx = threadIdx.x & 31, ty = threadIdx.x >> 5;
    #pragma unroll
    for (int j = 0; j < 4; j++)
        tile[ty + j*8][tx] = w[(size_t)(k0 + ty + j*8) * N + n0 + tx];
    __syncthreads();
    #pragma unroll
    for (int j = 0; j < 4; j++)
        dst[(size_t)(nbase + n0 + ty + j*8) * 2048 + k0 + tx] = f2b(tile[tx][ty + j*8]);
}

// ---------- QKV GEMM, BK=64, 32x32x16 MFMA, fused RoPE + V-transpose -------
// 128x128 tile, BK=64, XOR-swizzled LDS (slot = chunk^(row&7)) -> frag b128
// reads: 8 lanes per 4-bank group = LDS floor, 0 conflicts (r9-verified).
// Wave tile 64x64 = 2x2 of 32x32x16 MFMA: 16 MFMA/iter @8.07cyc (=129cyc)
// vs 32 @4.85 (=155cyc) -> -17% MFMA pipe + half the issue slots.
// C/D layout: col=lane&31, row=(reg&3)+8*(reg>>2)+4*(lane>>5) [m74/m101].
__global__ __launch_bounds__(256)
void gemm_qkv(const unsigned short* __restrict__ A,
              const unsigned short* __restrict__ BT,
              unsigned short* __restrict__ qkv,
              unsigned short* __restrict__ vT,
              const float* __restrict__ freqs) {
    __shared__ unsigned short As[128 * 64];
    __shared__ unsigned short Bs[128 * 64];

    int tid  = threadIdx.x;
    int lane = tid & 63, w = tid >> 6;
    int l31 = lane & 31, h = lane >> 5;
    int row0 = blockIdx.y * 128, col0 = blockIdx.x * 128;
    int wm = (w & 1) * 64, wn = (w >> 1) * 64;

    f32x16 acc[2][2];
    #pragma unroll
    for (int i = 0; i < 2; i++)
        #pragma unroll
        for (int j = 0; j < 2; j++)
            #pragma unroll
            for (int r = 0; r < 16; r++) acc[i][j][r] = 0.f;

    const unsigned short* Arow = A  + (size_t)row0 * 2048;
    const unsigned short* Brow = BT + (size_t)col0 * 2048;

    for (int k0 = 0; k0 < 2048; k0 += 64) {
        #pragma unroll
        for (int it = 0; it < 4; it++) {
            int c = w * 256 + it * 64 + lane;          // chunk 0..1023
            int r = c >> 3, qp = c & 7;
            int q8 = (qp ^ (r & 7)) * 8;               // inverse swizzle
            __builtin_amdgcn_global_load_lds(
                (gas_p)(Arow + (size_t)r * 2048 + k0 + q8),
                (las_p)((char*)&As[0] + (size_t)(w * 256 + it * 64) * 16),
                16, 0, 0);
            __builtin_amdgcn_global_load_lds(
                (gas_p)(Brow + (size_t)r * 2048 + k0 + q8),
                (las_p)((char*)&Bs[0] + (size_t)(w * 256 + it * 64) * 16),
                16, 0, 0);
        }
        __syncthreads();
        #pragma unroll
        for (int kk = 0; kk < 4; kk++) {               // 4 K=16 steps
            int chunk = kk * 2 + h;                    // k = kk*16 + h*8
            bf16x8 af[2], bf[2];
            #pragma unroll
            for (int i = 0; i < 2; i++) {
                int row = wm + i*32 + l31;
                af[i] = *(const bf16x8*)&As[row * 64 + (chunk ^ (row & 7)) * 8];
            }
            #pragma unroll
            for (int j = 0; j < 2; j++) {
                int row = wn + j*32 + l31;
                bf[j] = *(const bf16x8*)&Bs[row * 64 + (chunk ^ (row & 7)) * 8];
            }
            #pragma unroll
            for (int i = 0; i < 2; i++)
                #pragma unroll
                for (int j = 0; j < 2; j++)
                    acc[i][j] = __builtin_amdgcn_mfma_f32_32x32x16_bf16(af[i], bf[j], acc[i][j], 0, 0, 0);
        }
        __syncthreads();
    }

    bool isV = (col0 >= 2560);
    #pragma unroll
    for (int i = 0; i < 2; i++) {
        #pragma unroll
        for (int j = 0; j < 2; j++) {
            int colb = col0 + wn + j*32 + l31;
            if (!isV) {
                int dd = (colb & 127) & ~1;
                bool odd = colb & 1;
                #pragma unroll
                for (int rg = 0; rg < 4; rg++) {
                    int mbase = row0 + wm + i*32 + rg*8 + 4*h;
                    #pragma unroll
                    for (int rr = 0; rr < 4; rr++) {
                        int m = mbase + rr;
                        int s = m & 2047;
                        float v  = acc[i][j][rg*4 + rr];
                        float pv = __shfl_xor(v, 1);
                        float cs = freqs[s*128 + dd];
                        float sn = freqs[s*128 + dd + 1];
                        float o  = odd ? (pv*sn + v*cs) : (v*cs - pv*sn);
                        qkv[(size_t)m * NQKV + colb] = f2b(o);
                    }
                }
            } else {
                int vrow = (row0 >> 11) * 512 + (colb - 2560);
                #pragma unroll
                for (int rg = 0; rg < 4; rg++) {
                    int s0g = (row0 + wm + i*32 + rg*8 + 4*h) & 2047;
                    ushort4 ov;
                    ov.x = f2b(acc[i][j][rg*4 + 0]);
                    ov.y = f2b(acc[i][j][rg*4 + 1]);
                    ov.z = f2b(acc[i][j][rg*4 + 2]);
                    ov.w = f2b(acc[i][j][rg*4 + 3]);
                    *(ushort4*)(vT + (size_t)vrow * 2048 + s0g) = ov;
                }
            }
        }
    }
}

// ---------- output projection GEMM, BK=64, 32x32x16 MFMA -------------------
__global__ __launch_bounds__(256)
void gemm_out(const unsigned short* __restrict__ A,
              const unsigned short* __restrict__ BT,
              float* __restrict__ C, int N) {
    __shared__ unsigned short As[128 * 64];
    __shared__ unsigned short Bs[128 * 64];

    int tid  = threadIdx.x;
    int lane = tid & 63, w = tid >> 6;
    int l31 = lane & 31, h = lane >> 5;
    int row0 = blockIdx.y * 128, col0 = blockIdx.x * 128;
    int wm = (w & 1) * 64, wn = (w >> 1) * 64;

    f32x16 acc[2][2];
    #pragma unroll
    for (int i = 0; i < 2; i++)
        #pragma unroll
        for (int j = 0; j < 2; j++)
            #pragma unroll
            for (int r = 0; r < 16; r++) acc[i][j][r] = 0.f;

    const unsigned short* Arow = A  + (size_t)row0 * 2048;
    const unsigned short* Brow = BT + (size_t)col0 * 2048;

    for (int k0 = 0; k0 < 2048; k0 += 64) {
        #pragma unroll
        for (int it = 0; it < 4; it++) {
            int c = w * 256 + it * 64 + lane;
            int r = c >> 3, qp = c & 7;
            int q8 = (qp ^ (r & 7)) * 8;
            __builtin_amdgcn_global_load_lds(
                (gas_p)(Arow + (size_t)r * 2048 + k0 + q8),
                (las_p)((char*)&As[0] + (size_t)(w * 256 + it * 64) * 16),
                16, 0, 0);
            __builtin_amdgcn_global_load_lds(
                (gas_p)(Brow + (size_t)r * 2048 + k0 + q8),
                (las_p)((char*)&Bs[0] + (size_t)(w * 256 + it * 64) * 16),
                16, 0, 0);
        }
        __syncthreads();
        #pragma unroll
        for (int kk = 0; kk < 4; kk++) {
            int chunk = kk * 2 + h;
            bf16x8 af[2], bf[2];
            #pragma unroll
            for (int i = 0; i < 2; i++) {
                int row = wm + i*32 + l31;
                af[i] = *(const bf16x8*)&As[row * 64 + (chunk ^ (row & 7)) * 8];
            }
            #pragma unroll
            for (int j = 0; j < 2; j++) {
                int row = wn + j*32 + l31;
                bf[j] = *(const bf16x8*)&Bs[row * 64 + (chunk ^ (row & 7)) * 8];
            }
            #pragma unroll
            for (int i = 0; i < 2; i++)
                #pragma unroll
                for (int j = 0; j < 2; j++)
                    acc[i][j] = __builtin_amdgcn_mfma_f32_32x32x16_bf16(af[i], bf[j], acc[i][j], 0, 0, 0);
        }
        __syncthreads();
    }

    #pragma unroll
    for (int i = 0; i < 2; i++)
        #pragma unroll
        for (int j = 0; j < 2; j++) {
            int colb = col0 + wn + j*32 + l31;
            #pragma unroll
            for (int rg = 0; rg < 4; rg++) {
                int m = row0 + wm + i*32 + rg*8 + 4*h;
                #pragma unroll
                for (int rr = 0; rr < 4; rr++)
                    C[(size_t)(m + rr) * N + colb] = acc[i][j][rg*4 + rr];
            }
        }
}

// ---------- GQA-fused MFMA flash attention (unchanged from r8) -------------
__global__ __launch_bounds__(512)
void attn_mfma(const unsigned short* __restrict__ qkv,
               const unsigned short* __restrict__ vT,
               unsigned short* __restrict__ ao,
               unsigned short* __restrict__ wsP,
               float2* __restrict__ wsML) {
    __shared__ unsigned short Ks[64 * 128];   // 16KB, XOR-swizzled
    __shared__ unsigned short Vt[128 * 64];   // 16KB, XOR-swizzled

    int tid  = threadIdx.x;
    int lane = tid & 63, w = tid >> 6;        // w in 0..7
    int quad = lane >> 4, l15 = lane & 15;
    int hw = w >> 1, qhalf = w & 1;
    int bx = blockIdx.x, hk = blockIdx.y, b = blockIdx.z;
    int h = hk * 4 + hw;

    int qt, c;
    if (bx < 12)      { qt = 31 - bx / 3;        c = bx % 3; }
    else if (bx < 40) { qt = 27 - (bx - 12) / 2; c = (bx - 12) & 1; }
    else              { qt = 53 - bx;            c = 0; }
    int nt = qt + 1;
    int nch = (qt >= 28) ? 3 : (qt >= 14 ? 2 : 1);
    int kt_begin = c * 14;
    int kt_end = (nt < (c + 1) * 14) ? nt : (c + 1) * 14;
    bool lastc = (c == nch - 1);
    int q0 = qt * 64;
    const float scale = 0.08838834764831845f;   // 1/sqrt(128)

    bf16x8 aq[2][4];
    #pragma unroll
    for (int qf = 0; qf < 2; qf++) {
        const unsigned short* qrow =
            qkv + (size_t)(b*2048 + q0 + qhalf*32 + qf*16 + l15) * NQKV + h*128;
        #pragma unroll
        for (int k4 = 0; k4 < 4; k4++)
            aq[qf][k4] = *(const bf16x8*)(qrow + k4*32 + quad*8);
    }

    int koff[4][4];
    #pragma unroll
    for (int j = 0; j < 4; j++) {
        int row = ((j >> 1) * 32) + ((l15 >> 2) * 8) + ((j & 1) * 4) + (l15 & 3);
        #pragma unroll
        for (int k4 = 0; k4 < 4; k4++) {
            int slot = (k4 * 4 + quad) ^ (row & 15);
            koff[j][k4] = (row * 16 + slot) * 8;
        }
    }
    int vbase0 = (l15 * 8 + (quad ^ (l15 & 7))) * 8;
    int vbase1 = (l15 * 8 + ((4 + quad) ^ (l15 & 7))) * 8;

    const unsigned short* kb0 = qkv + (size_t)(b*2048) * NQKV + 2048 + hk*128;
    const unsigned short* vb0 = vT + (size_t)(b*512 + hk*128) * 2048;

    auto stage_k = [&](int kt) {
        #pragma unroll
        for (int it = 0; it < 2; it++) {
            int s = w * 128 + it * 64 + lane;
            int r = s >> 4, qp = s & 15;
            int q = qp ^ (r & 15);
            __builtin_amdgcn_global_load_lds(
                (gas_p)(kb0 + (size_t)(kt*64 + r) * NQKV + q * 8),
                (las_p)((char*)&Ks[0] + (w * 128 + it * 64) * 16),
                16, 0, 0);
        }
    };
    auto stage_v = [&](int kt) {
        #pragma unroll
        for (int it = 0; it < 2; it++) {
            int s = w * 128 + it * 64 + lane;
            int r = s >> 3, qp = s & 7;
            int q = qp ^ (r & 7);
            __builtin_amdgcn_global_load_lds(
                (gas_p)(vb0 + (size_t)r * 2048 + kt*64 + q * 8),
                (las_p)((char*)&Vt[0] + (w * 128 + it * 64) * 16),
                16, 0, 0);
        }
    };

    f32x4 o_acc[2][8];
    const f32x4 zf = {0.f, 0.f, 0.f, 0.f};
    #pragma unroll
    for (int qf = 0; qf < 2; qf++)
        #pragma unroll
        for (int jn = 0; jn < 8; jn++) o_acc[qf][jn] = zf;
    float m_i[2] = {-1e30f, -1e30f}, l_i[2] = {0.f, 0.f};
    int qglob[2] = {q0 + qhalf*32 + l15, q0 + qhalf*32 + 16 + l15};

    stage_k(kt_begin);
    for (int kt = kt_begin; kt < kt_end; kt++) {
        __syncthreads();             // A: K(kt) landed; V buffer free
        stage_v(kt);                 // async during QK+softmax

        f32x4 s_acc[2][4];
        #pragma unroll
        for (int j = 0; j < 4; j++) {
            s_acc[0][j] = zf; s_acc[1][j] = zf;
            #pragma unroll
            for (int k4 = 0; k4 < 4; k4++) {
                bf16x8 ak = *(const bf16x8*)&Ks[koff[j][k4]];
                s_acc[0][j] = __builtin_amdgcn_mfma_f32_16x16x32_bf16(ak, aq[0][k4], s_acc[0][j], 0, 0, 0);
                s_acc[1][j] = __builtin_amdgcn_mfma_f32_16x16x32_bf16(ak, aq[1][k4], s_acc[1][j], 0, 0, 0);
            }
        }

        bf16x8 pp[2][2];
        #pragma unroll
        for (int qf = 0; qf < 2; qf++) {
            float sv[4][4];
            #pragma unroll
            for (int j = 0; j < 4; j++)
                #pragma unroll
                for (int r = 0; r < 4; r++)
                    sv[j][r] = s_acc[qf][j][r] * scale;
            if (kt == qt) {
                #pragma unroll
                for (int j = 0; j < 4; j++)
                    #pragma unroll
                    for (int r = 0; r < 4; r++) {
                        int sloc = ((j >> 1) * 32) + quad*8 + ((j & 1) * 4) + r;
                        if (kt*64 + sloc > qglob[qf]) sv[j][r] = -1e30f;
                    }
            }
            float mx = sv[0][0];
            #pragma unroll
            for (int j = 0; j < 4; j++)
                #pragma unroll
                for (int r = 0; r < 4; r++) mx = fmaxf(mx, sv[j][r]);
            mx = fmaxf(mx, __shfl_xor(mx, 16));
            mx = fmaxf(mx, __shfl_xor(mx, 32));
            float mnew = fmaxf(m_i[qf], mx);
            float alpha = __expf(m_i[qf] - mnew);
            float rs = 0.f;
            float p[4][4];
            #pragma unroll
            for (int j = 0; j < 4; j++)
                #pragma unroll
                for (int r = 0; r < 4; r++) {
                    p[j][r] = __expf(sv[j][r] - mnew);
                    rs += p[j][r];
                }
            l_i[qf] = l_i[qf] * alpha + rs;
            m_i[qf] = mnew;
            #pragma unroll
            for (int jn = 0; jn < 8; jn++)
                #pragma unroll
                for (int r = 0; r < 4; r++) o_acc[qf][jn][r] *= alpha;
            #pragma unroll
            for (int r = 0; r < 4; r++) {
                pp[qf][0][r]     = (short)f2b(p[0][r]);
                pp[qf][0][r + 4] = (short)f2b(p[1][r]);
                pp[qf][1][r]     = (short)f2b(p[2][r]);
                pp[qf][1][r + 4] = (short)f2b(p[3][r]);
            }
        }

        __syncthreads();             // B: V(kt) landed; K buffer free
        if (kt + 1 < kt_end) stage_k(kt + 1);

        #pragma unroll
        for (int jn = 0; jn < 8; jn++) {
            bf16x8 av0 = *(const bf16x8*)&Vt[jn*1024 + vbase0];
            bf16x8 av1 = *(const bf16x8*)&Vt[jn*1024 + vbase1];
            o_acc[0][jn] = __builtin_amdgcn_mfma_f32_16x16x32_bf16(av0, pp[0][0], o_acc[0][jn], 0, 0, 0);
            o_acc[0][jn] = __builtin_amdgcn_mfma_f32_16x16x32_bf16(av1, pp[0][1], o_acc[0][jn], 0, 0, 0);
            o_acc[1][jn] = __builtin_amdgcn_mfma_f32_16x16x32_bf16(av0, pp[1][0], o_acc[1][jn], 0, 0, 0);
            o_acc[1][jn] = __builtin_amdgcn_mfma_f32_16x16x32_bf16(av1, pp[1][1], o_acc[1][jn], 0, 0, 0);
        }
    }

    int pi = 0, mi = 0;
    if (qt >= 14) {
        if (qt < 28) { mi = (qt - 14) * 2 + c;       pi = qt - 14; }
        else         { mi = 28 + (qt - 28) * 3 + c;  pi = 14 + (qt - 28) * 2 + c; }
    }
    #pragma unroll
    for (int qf = 0; qf < 2; qf++) {
        float lt = l_i[qf];
        lt += __shfl_xor(lt, 16);
        lt += __shfl_xor(lt, 32);
        float inv = 1.f / lt;
        int q_local = qhalf * 32 + qf * 16 + l15;
        unsigned short* dst;
        if (lastc)
            dst = ao + (size_t)(b*2048 + q0 + q_local) * 2048 + h*128;
        else
            dst = wsP + (size_t)(((pi * 8 + hk * 2 + b) * 4 + hw) * 64 + q_local) * 128;
        #pragma unroll
        for (int jn = 0; jn < 8; jn++) {
            ushort4 ov;
            ov.x = f2b(o_acc[qf][jn][0] * inv);
            ov.y = f2b(o_acc[qf][jn][1] * inv);
            ov.z = f2b(o_acc[qf][jn][2] * inv);
            ov.w = f2b(o_acc[qf][jn][3] * inv);
            *(ushort4*)(dst + jn*16 + quad*4) = ov;
        }
        if (qt >= 14 && quad == 0)
            wsML[(mi * 8 + hk * 2 + b) * 256 + hw * 64 + q_local]
                = make_float2(m_i[qf], lt);
    }
}

// ---------- merge split-K partials (rows q >= 896, 2-3 chunks) -------------
__global__ __launch_bounds__(256)
void merge_kernel(unsigned short* __restrict__ ao,
                  const unsigned short* __restrict__ wsP,
                  const float2* __restrict__ wsML) {
    int t = blockIdx.x * 256 + threadIdx.x;
    int d = (t & 15) * 8;
    int h = (t >> 4) & 15;
    int rest = t >> 8;                // 0..2303
    int q_off = rest % 1152;
    int b = rest / 1152;
    int q = 896 + q_off;
    int qt = q >> 6, q_local = q & 63;
    int hk = h >> 2, hw = h & 3;
    int nch = (qt >= 28) ? 3 : 2;

    float mv[3], lv[3];
    for (int cc = 0; cc < nch; cc++) {
        int mi = (qt < 28) ? (qt - 14) * 2 + cc : 28 + (qt - 28) * 3 + cc;
        float2 ml = wsML[(mi * 8 + hk * 2 + b) * 256 + hw * 64 + q_local];
        mv[cc] = ml.x; lv[cc] = ml.y;
    }
    float M = mv[0];
    for (int cc = 1; cc < nch; cc++) M = fmaxf(M, mv[cc]);
    float f[3], S = 0.f;
    for (int cc = 0; cc < nch; cc++) { f[cc] = __expf(mv[cc] - M) * lv[cc]; S += f[cc]; }
    float inv = 1.f / S;

    unsigned short* arow = ao + (size_t)(b*2048 + q) * 2048 + h*128 + d;
    float outv[8];
    {
        ushort4 a0 = *(ushort4*)arow, a1 = *(ushort4*)(arow + 4);
        float fl = f[nch-1];
        outv[0] = fl*b2f(a0.x); outv[1] = fl*b2f(a0.y);
        outv[2] = fl*b2f(a0.z); outv[3] = fl*b2f(a0.w);
        outv[4] = fl*b2f(a1.x); outv[5] = fl*b2f(a1.y);
        outv[6] = fl*b2f(a1.z); outv[7] = fl*b2f(a1.w);
    }
    for (int cc = 0; cc < nch - 1; cc++) {
        int pi = (qt < 28) ? (qt - 14) : 14 + (qt - 28) * 2 + cc;
        const unsigned short* prow =
            wsP + (size_t)(((pi * 8 + hk * 2 + b) * 4 + hw) * 64 + q_local) * 128 + d;
        ushort4 p0 = *(const ushort4*)prow, p1 = *(const ushort4*)(prow + 4);
        float fc = f[cc];
        outv[0] += fc*b2f(p0.x); outv[1] += fc*b2f(p0.y);
        outv[2] += fc*b2f(p0.z); outv[3] += fc*b2f(p0.w);
        outv[4] += fc*b2f(p1.x); outv[5] += fc*b2f(p1.y);
        outv[6] += fc*b2f(p1.z); outv[7] += fc*b2f(p1.w);
    }
    ushort4 o0, o1;
    o0.x = f2b(outv[0]*inv); o0.y = f2b(outv[1]*inv);
    o0.z = f2b(outv[2]*inv); o0.w = f2b(outv[3]*inv);
    o1.x = f2b(outv[4]*inv); o1.y = f2b(outv[5]*inv);
    o1.z = f2b(outv[6]*inv); o1.w = f2b(outv[7]*inv);
    *(ushort4*)arow = o0;
    *(ushort4*)(arow + 4) = o1;
}

// ---------- launch ---------------------------------------------------------
extern "C" void kernel_launch(void* const* d_in, const int* in_sizes, int n_in,
                              void* d_out, int out_size, void* d_ws, size_t ws_size,
                              hipStream_t stream) {
    const float* x     = (const float*)d_in[0];
    const float* freqs = (const float*)d_in[1];
    const float* wq    = (const float*)d_in[2];
    const float* wk    = (const float*)d_in[3];
    const float* wv    = (const float*)d_in[4];
    const float* wo    = (const float*)d_in[5];
    float* out = (float*)d_out;

    char* ws = (char*)d_ws;
    unsigned short* xbf    = (unsigned short*)(ws);                  // 16MB
    unsigned short* aobuf  = (unsigned short*)(ws);                  // alias (xbf dead)
    unsigned short* wqkvT  = (unsigned short*)(ws + (16u<<20));      // 12MB
    unsigned short* woT    = (unsigned short*)(ws + (28u<<20));      // 8MB
    unsigned short* qkvbuf = (unsigned short*)(ws + (36u<<20));      // 24MB
    unsigned short* vTbuf  = (unsigned short*)(ws + (60u<<20));      // 4MB
    unsigned short* wsP  = (unsigned short*)(ws + (16u<<20));        // 11MB (aliases wqkvT, dead)
    float2*         wsML = (float2*)(ws + (16u<<20) + 176u*65536u);  // 640KB

    dim3 blk(256);
    convert_x<<<8192, blk, 0, stream>>>(x, xbf);
    convert_w_all<<<dim3(64, 64, 4), blk, 0, stream>>>(wq, wk, wv, wo, wqkvT, woT);
    gemm_qkv<<<dim3(NQKV/128, M_/128), blk, 0, stream>>>(xbf, wqkvT, qkvbuf, vTbuf, freqs);
    attn_mfma<<<dim3(54, 4, 2), dim3(512), 0, stream>>>(qkvbuf, vTbuf, aobuf, wsP, wsML);
    merge_kernel<<<2304, blk, 0, stream>>>(aobuf, wsP, wsML);
    gemm_out<<<dim3(2048/128, M_/128), blk, 0, stream>>>(aobuf, woT, out, 2048);
}